// Round 1
// baseline (15321.875 us; speedup 1.0000x reference)
//
#include <hip/hip_runtime.h>
#include <cstdint>
#include <cstddef>

namespace {

constexpr int N_ITEMS = 10000;
constexpr int N_TAGS  = 2000;
constexpr int VOCAB   = 50000;
constexpr int KTAG    = 32;
constexpr int KITEM   = 8;
constexpr int HD      = 128;
constexpr int NLAYER  = 4;

__device__ __forceinline__ float sigm(float x)   { return 1.0f / (1.0f + __expf(-x)); }
__device__ __forceinline__ float tanhft(float x) { return 1.0f - 2.0f / (1.0f + __expf(2.0f * x)); }

__device__ __forceinline__ void fma4(float& acc, const float4 w, const float4 v) {
  acc = fmaf(w.x, v.x, acc);
  acc = fmaf(w.y, v.y, acc);
  acc = fmaf(w.z, v.z, acc);
  acc = fmaf(w.w, v.w, acc);
}

__device__ __forceinline__ float4 unpack_bf4(uint2 u) {
  float4 r;
  r.x = __uint_as_float(u.x << 16);
  r.y = __uint_as_float(u.x & 0xffff0000u);
  r.z = __uint_as_float(u.y << 16);
  r.w = __uint_as_float(u.y & 0xffff0000u);
  return r;
}

__global__ void zero_i32(int* p, int n) {
  int i = blockIdx.x * blockDim.x + threadIdx.x;
  if (i < n) p[i] = 0;
}

__global__ void mark_k(const int* __restrict__ items, int* __restrict__ present) {
  int i = blockIdx.x * blockDim.x + threadIdx.x;
  if (i < N_ITEMS) present[items[i]] = 1;
}

// single-block exclusive scan over present[0..VOCAB) -> rank; rank[VOCAB] = total
__global__ __launch_bounds__(1024) void scan_k(const int* __restrict__ present,
                                               int* __restrict__ rank) {
  __shared__ int tmp[1024];
  const int tid  = threadIdx.x;
  const int CH   = 49;          // 1024*49 >= 50000
  const int base = tid * CH;
  int s = 0;
  for (int j = 0; j < CH; j++) { int idx = base + j; if (idx < VOCAB) s += present[idx]; }
  tmp[tid] = s;
  __syncthreads();
  for (int off = 1; off < 1024; off <<= 1) {
    int v = (tid >= off) ? tmp[tid - off] : 0;
    __syncthreads();
    tmp[tid] += v;
    __syncthreads();
  }
  int run = tmp[tid] - s;       // exclusive prefix
  for (int j = 0; j < CH; j++) {
    int idx = base + j;
    if (idx < VOCAB) { rank[idx] = run; run += present[idx]; }
  }
  if (tid == 1023) rank[VOCAB] = run;
}

__global__ void build_k(const int* __restrict__ present, const int* __restrict__ rank,
                        const float* __restrict__ table, float* __restrict__ hi) {
  int gid = blockIdx.x * blockDim.x + threadIdx.x;
  if (gid >= VOCAB * 32) return;
  int v = gid >> 5, q = gid & 31;
  if (present[v]) {
    int slot = rank[v];
    reinterpret_cast<float4*>(hi + (size_t)slot * HD)[q] =
        reinterpret_cast<const float4*>(table + (size_t)v * HD)[q];
  }
}

__global__ void pad_k(const int* __restrict__ rank, const float* __restrict__ table,
                      float* __restrict__ hi) {
  int gid = blockIdx.x * blockDim.x + threadIdx.x;
  if (gid >= N_ITEMS * 32) return;
  int slot = gid >> 5, q = gid & 31;
  if (slot >= rank[VOCAB]) {   // padding slots: fill_value = 0 -> item_table[0]
    reinterpret_cast<float4*>(hi + (size_t)slot * HD)[q] =
        reinterpret_cast<const float4*>(table)[q];
  }
}

__global__ void inv_k(const int* __restrict__ items, const int* __restrict__ rank,
                      int* __restrict__ inv) {
  int i = blockIdx.x * blockDim.x + threadIdx.x;
  if (i < N_ITEMS) inv[i] = rank[items[i]];
}

__global__ void tobf16_k(const float* __restrict__ in, uint16_t* __restrict__ out, int n) {
  int i = blockIdx.x * blockDim.x + threadIdx.x;
  if (i < n) {
    uint32_t u = __float_as_uint(in[i]);
    u += 0x7fffu + ((u >> 16) & 1u);   // RNE
    out[i] = (uint16_t)(u >> 16);
  }
}

struct ConvArgs {
  const float* hsrc; const float* hdst;
  const int* nbr; const int* len;
  const uint16_t* Wih; const uint16_t* Whh;   // bf16 [512,128] layer slice
  const float* bih; const float* bhh;         // [512]
  const float* Wself; const float* Wneigh;    // [128,128]
  const float* bvec;                          // [128]
  const float* gamma; const float* beta;      // [128] (item side only)
  float* out;
  int K; int ln; int nblk;
};

// one block = 8 destination nodes; 256 threads: d = tid&127, half = tid>>7 owns 4 nodes
__global__ __launch_bounds__(256)
void layer_k(ConvArgs targ, ConvArgs iarg) {
  const bool is_tag = ((int)blockIdx.x < targ.nblk);
  const ConvArgs& a = is_tag ? targ : iarg;
  const int blk  = is_tag ? (int)blockIdx.x : ((int)blockIdx.x - targ.nblk);
  const int tid  = threadIdx.x;
  const int d    = tid & 127;
  const int half = tid >> 7;
  const int n0   = blk * 8;
  const int K    = a.K;

  __shared__ __align__(16) float xs[8][HD];
  __shared__ __align__(16) float hs[8][HD];
  __shared__ int lens_s[8];

  if (tid < 8) lens_s[tid] = a.len[n0 + tid];
  hs[half * 4 + 0][d] = 0.f; hs[half * 4 + 1][d] = 0.f;
  hs[half * 4 + 2][d] = 0.f; hs[half * 4 + 3][d] = 0.f;
  __syncthreads();

  int lenr[4];
  #pragma unroll
  for (int j = 0; j < 4; j++) lenr[j] = lens_s[half * 4 + j];
  int tmax = lens_s[0];
  #pragma unroll
  for (int b = 1; b < 8; b++) tmax = (lens_s[b] > tmax) ? lens_s[b] : tmax;

  const float bi0 = a.bih[d]       + a.bhh[d];
  const float bf0 = a.bih[128 + d] + a.bhh[128 + d];
  const float bg0 = a.bih[256 + d] + a.bhh[256 + d];
  const float bo0 = a.bih[384 + d] + a.bhh[384 + d];

  const uint16_t* wi0 = a.Wih + (size_t)d * HD;
  const uint16_t* wi1 = a.Wih + (size_t)(128 + d) * HD;
  const uint16_t* wi2 = a.Wih + (size_t)(256 + d) * HD;
  const uint16_t* wi3 = a.Wih + (size_t)(384 + d) * HD;
  const uint16_t* wh0 = a.Whh + (size_t)d * HD;
  const uint16_t* wh1 = a.Whh + (size_t)(128 + d) * HD;
  const uint16_t* wh2 = a.Whh + (size_t)(256 + d) * HD;
  const uint16_t* wh3 = a.Whh + (size_t)(384 + d) * HD;

  float cc[4] = {0.f, 0.f, 0.f, 0.f};

  for (int t = 0; t < tmax; ++t) {
    { // gather x_t: 256 threads cover 8 rows x 32 float4
      int b = tid >> 5, q = tid & 31;
      if (t < lens_s[b]) {
        int idx = a.nbr[(size_t)(n0 + b) * K + t];
        reinterpret_cast<float4*>(xs[b])[q] =
            reinterpret_cast<const float4*>(a.hsrc + (size_t)idx * HD)[q];
      }
    }
    __syncthreads();

    float g0[4], g1[4], g2[4], g3[4];
    #pragma unroll
    for (int j = 0; j < 4; j++) { g0[j] = bi0; g1[j] = bf0; g2[j] = bg0; g3[j] = bo0; }

    #pragma unroll 4
    for (int k4 = 0; k4 < 32; k4++) {
      const float4 fi0 = unpack_bf4(*reinterpret_cast<const uint2*>(wi0 + k4 * 4));
      const float4 fi1 = unpack_bf4(*reinterpret_cast<const uint2*>(wi1 + k4 * 4));
      const float4 fi2 = unpack_bf4(*reinterpret_cast<const uint2*>(wi2 + k4 * 4));
      const float4 fi3 = unpack_bf4(*reinterpret_cast<const uint2*>(wi3 + k4 * 4));
      const float4 fh0 = unpack_bf4(*reinterpret_cast<const uint2*>(wh0 + k4 * 4));
      const float4 fh1 = unpack_bf4(*reinterpret_cast<const uint2*>(wh1 + k4 * 4));
      const float4 fh2 = unpack_bf4(*reinterpret_cast<const uint2*>(wh2 + k4 * 4));
      const float4 fh3 = unpack_bf4(*reinterpret_cast<const uint2*>(wh3 + k4 * 4));
      #pragma unroll
      for (int j = 0; j < 4; j++) {
        if (t < lenr[j]) {   // uniform per block-half
          const int b = half * 4 + j;
          const float4 x4 = reinterpret_cast<const float4*>(xs[b])[k4];
          const float4 h4 = reinterpret_cast<const float4*>(hs[b])[k4];
          fma4(g0[j], fi0, x4); fma4(g0[j], fh0, h4);
          fma4(g1[j], fi1, x4); fma4(g1[j], fh1, h4);
          fma4(g2[j], fi2, x4); fma4(g2[j], fh2, h4);
          fma4(g3[j], fi3, x4); fma4(g3[j], fh3, h4);
        }
      }
    }
    __syncthreads();

    #pragma unroll
    for (int j = 0; j < 4; j++) {
      if (t < lenr[j]) {
        const float iv = sigm(g0[j]);
        const float fv = sigm(g1[j]);
        const float gv = tanhft(g2[j]);
        const float ov = sigm(g3[j]);
        const float cn = fmaf(fv, cc[j], iv * gv);
        cc[j] = cn;
        hs[half * 4 + j][d] = ov * tanhft(cn);
      }
    }
    // no barrier needed here: next gather only writes xs; next gate-read of hs is
    // ordered by the post-gather barrier.
  }

  // ---- epilogue: out = hdst @ Wself^T + hn @ Wneigh^T + b (then optional LN) ----
  {
    int b = tid >> 5, q = tid & 31;
    reinterpret_cast<float4*>(xs[b])[q] =
        reinterpret_cast<const float4*>(a.hdst + (size_t)(n0 + b) * HD)[q];
  }
  __syncthreads();

  float ov[4];
  const float bd = a.bvec[d];
  #pragma unroll
  for (int j = 0; j < 4; j++) ov[j] = bd;

  const float4* wsp = reinterpret_cast<const float4*>(a.Wself  + (size_t)d * HD);
  const float4* wnp = reinterpret_cast<const float4*>(a.Wneigh + (size_t)d * HD);
  #pragma unroll 4
  for (int k4 = 0; k4 < 32; k4++) {
    const float4 aa = wsp[k4], ee = wnp[k4];
    #pragma unroll
    for (int j = 0; j < 4; j++) {
      const int b = half * 4 + j;
      const float4 hd4 = reinterpret_cast<const float4*>(xs[b])[k4];
      const float4 hn4 = reinterpret_cast<const float4*>(hs[b])[k4];
      fma4(ov[j], aa, hd4);
      fma4(ov[j], ee, hn4);
    }
  }

  if (!a.ln) {
    #pragma unroll
    for (int j = 0; j < 4; j++)
      a.out[(size_t)(n0 + half * 4 + j) * HD + d] = ov[j];
  } else {
    __syncthreads();
    #pragma unroll
    for (int j = 0; j < 4; j++) xs[half * 4 + j][d] = ov[j];
    __syncthreads();
    const int b = tid >> 5, l = tid & 31;   // 32 lanes per row
    float s = 0.f, s2 = 0.f;
    float vloc[4];
    #pragma unroll
    for (int q = 0; q < 4; q++) {
      float v = xs[b][l + q * 32];
      vloc[q] = v; s += v; s2 += v * v;
    }
    #pragma unroll
    for (int off = 16; off >= 1; off >>= 1) {
      s  += __shfl_xor(s,  off);
      s2 += __shfl_xor(s2, off);
    }
    const float mu   = s  * (1.f / 128.f);
    const float var  = s2 * (1.f / 128.f) - mu * mu;
    const float istd = rsqrtf(var + 1e-5f);
    #pragma unroll
    for (int q = 0; q < 4; q++) {
      const int dd = l + q * 32;
      a.out[(size_t)(n0 + b) * HD + dd] =
          (vloc[q] - mu) * istd * a.gamma[dd] + a.beta[dd];
    }
  }
}

__global__ __launch_bounds__(128)
void final_k(const float* __restrict__ hi, const int* __restrict__ inv,
             const float* __restrict__ Wf, float* __restrict__ out) {
  __shared__ __align__(16) float row[HD];
  const int i  = blockIdx.x;
  const int dd = threadIdx.x;
  const int r  = inv[i];
  row[dd] = hi[(size_t)r * HD + dd];
  __syncthreads();
  float acc = 0.f;
  const float4* w  = reinterpret_cast<const float4*>(Wf + (size_t)dd * HD);
  const float4* rr = reinterpret_cast<const float4*>(row);
  #pragma unroll 8
  for (int k4 = 0; k4 < 32; k4++) fma4(acc, w[k4], rr[k4]);
  out[(size_t)i * HD + dd] = (acc > 0.f) ? acc : 0.01f * acc;
}

} // namespace

extern "C" void kernel_launch(void* const* d_in, const int* in_sizes, int n_in,
                              void* d_out, int out_size, void* d_ws, size_t ws_size,
                              hipStream_t stream) {
  (void)in_sizes; (void)n_in; (void)out_size; (void)ws_size;

  const int*   items      = (const int*)d_in[0];
  const int*   nbr_item   = (const int*)d_in[1];
  const int*   len_tag    = (const int*)d_in[2];
  const int*   nbr_tag    = (const int*)d_in[3];
  const int*   len_item   = (const int*)d_in[4];
  const float* item_table = (const float*)d_in[5];
  const float* tag_table  = (const float*)d_in[6];
  const float* Wih_as   = (const float*)d_in[7];
  const float* Whh_as   = (const float*)d_in[8];
  const float* bih_as   = (const float*)d_in[9];
  const float* bhh_as   = (const float*)d_in[10];
  const float* Wself_as  = (const float*)d_in[11];
  const float* Wneigh_as = (const float*)d_in[12];
  const float* b_as      = (const float*)d_in[13];
  const float* Wih_ras   = (const float*)d_in[14];
  const float* Whh_ras   = (const float*)d_in[15];
  const float* bih_ras   = (const float*)d_in[16];
  const float* bhh_ras   = (const float*)d_in[17];
  const float* Wself_ras  = (const float*)d_in[18];
  const float* Wneigh_ras = (const float*)d_in[19];
  const float* b_ras      = (const float*)d_in[20];
  const float* ln_gamma = (const float*)d_in[21];
  const float* ln_beta  = (const float*)d_in[22];
  const float* W_final  = (const float*)d_in[23];
  float* out = (float*)d_out;

  char* p = (char*)d_ws;
  auto take = [&](size_t bytes) -> char* {
    char* r = p;
    p += (bytes + 255) & ~(size_t)255;
    return r;
  };
  int* present = (int*)take((size_t)VOCAB * sizeof(int));
  int* rank    = (int*)take((size_t)(VOCAB + 1) * sizeof(int));
  int* invp    = (int*)take((size_t)N_ITEMS * sizeof(int));
  float* hiA = (float*)take((size_t)N_ITEMS * HD * sizeof(float));
  float* hiB = (float*)take((size_t)N_ITEMS * HD * sizeof(float));
  float* htA = (float*)take((size_t)N_TAGS * HD * sizeof(float));
  float* htB = (float*)take((size_t)N_TAGS * HD * sizeof(float));
  const int WSZ = NLAYER * 512 * HD;   // 262144 per tensor
  uint16_t* WihA = (uint16_t*)take((size_t)WSZ * 2);
  uint16_t* WhhA = (uint16_t*)take((size_t)WSZ * 2);
  uint16_t* WihR = (uint16_t*)take((size_t)WSZ * 2);
  uint16_t* WhhR = (uint16_t*)take((size_t)WSZ * 2);

  zero_i32<<<(VOCAB + 255) / 256, 256, 0, stream>>>(present, VOCAB);
  mark_k<<<(N_ITEMS + 255) / 256, 256, 0, stream>>>(items, present);
  scan_k<<<1, 1024, 0, stream>>>(present, rank);
  build_k<<<(VOCAB * 32 + 255) / 256, 256, 0, stream>>>(present, rank, item_table, hiA);
  pad_k<<<(N_ITEMS * 32 + 255) / 256, 256, 0, stream>>>(rank, item_table, hiA);
  inv_k<<<(N_ITEMS + 255) / 256, 256, 0, stream>>>(items, rank, invp);
  tobf16_k<<<(WSZ + 255) / 256, 256, 0, stream>>>(Wih_as, WihA, WSZ);
  tobf16_k<<<(WSZ + 255) / 256, 256, 0, stream>>>(Whh_as, WhhA, WSZ);
  tobf16_k<<<(WSZ + 255) / 256, 256, 0, stream>>>(Wih_ras, WihR, WSZ);
  tobf16_k<<<(WSZ + 255) / 256, 256, 0, stream>>>(Whh_ras, WhhR, WSZ);

  const float* hi_cur = hiA; float* hi_nxt = hiB;
  const float* ht_cur = tag_table; float* ht_nxt = htA;

  for (int l = 0; l < NLAYER; ++l) {
    ConvArgs ta, ia;
    ta.hsrc = hi_cur; ta.hdst = ht_cur;
    ta.nbr = nbr_item; ta.len = len_tag;
    ta.Wih = WihA + (size_t)l * 512 * HD; ta.Whh = WhhA + (size_t)l * 512 * HD;
    ta.bih = bih_as + (size_t)l * 512;    ta.bhh = bhh_as + (size_t)l * 512;
    ta.Wself = Wself_as + (size_t)l * HD * HD; ta.Wneigh = Wneigh_as + (size_t)l * HD * HD;
    ta.bvec = b_as + (size_t)l * HD;
    ta.gamma = nullptr; ta.beta = nullptr;
    ta.out = ht_nxt; ta.K = KTAG; ta.ln = 0; ta.nblk = N_TAGS / 8;

    ia.hsrc = ht_cur; ia.hdst = hi_cur;
    ia.nbr = nbr_tag; ia.len = len_item;
    ia.Wih = WihR + (size_t)l * 512 * HD; ia.Whh = WhhR + (size_t)l * 512 * HD;
    ia.bih = bih_ras + (size_t)l * 512;   ia.bhh = bhh_ras + (size_t)l * 512;
    ia.Wself = Wself_ras + (size_t)l * HD * HD; ia.Wneigh = Wneigh_ras + (size_t)l * HD * HD;
    ia.bvec = b_ras + (size_t)l * HD;
    ia.gamma = ln_gamma + (size_t)l * HD; ia.beta = ln_beta + (size_t)l * HD;
    ia.out = hi_nxt; ia.K = KITEM; ia.ln = 1; ia.nblk = N_ITEMS / 8;

    layer_k<<<ta.nblk + ia.nblk, 256, 0, stream>>>(ta, ia);

    hi_cur = hi_nxt; hi_nxt = (hi_cur == hiA) ? hiB : hiA;
    ht_cur = ht_nxt; ht_nxt = (ht_cur == htA) ? htB : htA;
  }

  final_k<<<N_ITEMS, 128, 0, stream>>>(hi_cur, invp, W_final, out);
}

// Round 2
// 3018.741 us; speedup vs baseline: 5.0756x; 5.0756x over previous
//
#include <hip/hip_runtime.h>
#include <cstdint>
#include <cstddef>

namespace {

constexpr int N_ITEMS = 10000;
constexpr int N_TAGS  = 2000;
constexpr int VOCAB   = 50000;
constexpr int KTAG    = 32;
constexpr int KITEM   = 8;
constexpr int HD      = 128;
constexpr int NLAYER  = 4;

__device__ __forceinline__ float sigm(float x)   { return 1.0f / (1.0f + __expf(-x)); }
__device__ __forceinline__ float tanhft(float x) { return 1.0f - 2.0f / (1.0f + __expf(2.0f * x)); }

__device__ __forceinline__ void fma4(float& acc, const float4 w, const float4 v) {
  acc = fmaf(w.x, v.x, acc);
  acc = fmaf(w.y, v.y, acc);
  acc = fmaf(w.z, v.z, acc);
  acc = fmaf(w.w, v.w, acc);
}

__device__ __forceinline__ float4 unpack_bf4(uint2 u) {
  float4 r;
  r.x = __uint_as_float(u.x << 16);
  r.y = __uint_as_float(u.x & 0xffff0000u);
  r.z = __uint_as_float(u.y << 16);
  r.w = __uint_as_float(u.y & 0xffff0000u);
  return r;
}

__global__ void zero_i32(int* p, int n) {
  int i = blockIdx.x * blockDim.x + threadIdx.x;
  if (i < n) p[i] = 0;
}

__global__ void mark_k(const int* __restrict__ items, int* __restrict__ present) {
  int i = blockIdx.x * blockDim.x + threadIdx.x;
  if (i < N_ITEMS) present[items[i]] = 1;
}

// single-block exclusive scan over present[0..VOCAB) -> rank; rank[VOCAB] = total
__global__ __launch_bounds__(1024) void scan_k(const int* __restrict__ present,
                                               int* __restrict__ rank) {
  __shared__ int tmp[1024];
  const int tid  = threadIdx.x;
  const int CH   = 49;          // 1024*49 >= 50000
  const int base = tid * CH;
  int s = 0;
  for (int j = 0; j < CH; j++) { int idx = base + j; if (idx < VOCAB) s += present[idx]; }
  tmp[tid] = s;
  __syncthreads();
  for (int off = 1; off < 1024; off <<= 1) {
    int v = (tid >= off) ? tmp[tid - off] : 0;
    __syncthreads();
    tmp[tid] += v;
    __syncthreads();
  }
  int run = tmp[tid] - s;       // exclusive prefix
  for (int j = 0; j < CH; j++) {
    int idx = base + j;
    if (idx < VOCAB) { rank[idx] = run; run += present[idx]; }
  }
  if (tid == 1023) rank[VOCAB] = run;
}

__global__ void build_k(const int* __restrict__ present, const int* __restrict__ rank,
                        const float* __restrict__ table, float* __restrict__ hi) {
  int gid = blockIdx.x * blockDim.x + threadIdx.x;
  if (gid >= VOCAB * 32) return;
  int v = gid >> 5, q = gid & 31;
  if (present[v]) {
    int slot = rank[v];
    reinterpret_cast<float4*>(hi + (size_t)slot * HD)[q] =
        reinterpret_cast<const float4*>(table + (size_t)v * HD)[q];
  }
}

__global__ void pad_k(const int* __restrict__ rank, const float* __restrict__ table,
                      float* __restrict__ hi) {
  int gid = blockIdx.x * blockDim.x + threadIdx.x;
  if (gid >= N_ITEMS * 32) return;
  int slot = gid >> 5, q = gid & 31;
  if (slot >= rank[VOCAB]) {   // padding slots: fill_value = 0 -> item_table[0]
    reinterpret_cast<float4*>(hi + (size_t)slot * HD)[q] =
        reinterpret_cast<const float4*>(table)[q];
  }
}

__global__ void inv_k(const int* __restrict__ items, const int* __restrict__ rank,
                      int* __restrict__ inv) {
  int i = blockIdx.x * blockDim.x + threadIdx.x;
  if (i < N_ITEMS) inv[i] = rank[items[i]];
}

// bf16 RNE + k4-interleaved layout: out[l][ (k>>2)*512 + row ][ k&3 ]
// so that at inner iteration k4, lanes d (= row mod 128) read CONSECUTIVE 8B.
__global__ void tobf16_il_k(const float* __restrict__ in, uint16_t* __restrict__ out, int total) {
  int i = blockIdx.x * blockDim.x + threadIdx.x;
  if (i >= total) return;
  int l = i >> 16;            // 512*128 = 65536 per layer
  int r = (i >> 7) & 511;     // row in [0,512)
  int k = i & 127;            // col in [0,128)
  uint32_t u = __float_as_uint(in[i]);
  u += 0x7fffu + ((u >> 16) & 1u);   // RNE
  int o = (l << 16) + ((((k >> 2) << 9) + r) << 2) + (k & 3);
  out[o] = (uint16_t)(u >> 16);
}

// ---- length bucketing (counting sort, descending length) ----
__global__ void hist_k(const int* __restrict__ len, int n, int* __restrict__ hist) {
  int i = blockIdx.x * blockDim.x + threadIdx.x;
  if (i < n) atomicAdd(&hist[len[i]], 1);
}

__global__ void base_k(const int* __restrict__ hist_tag, int* __restrict__ base_tag,
                       const int* __restrict__ hist_item, int* __restrict__ base_item) {
  if (threadIdx.x == 0) {
    int acc = 0;
    for (int l = KTAG; l >= 1; --l) { base_tag[l] = acc; acc += hist_tag[l]; }
    acc = 0;
    for (int l = KITEM; l >= 1; --l) { base_item[l] = acc; acc += hist_item[l]; }
  }
}

__global__ void scatter_k(const int* __restrict__ len, int n, int* __restrict__ base,
                          int* __restrict__ order) {
  int i = blockIdx.x * blockDim.x + threadIdx.x;
  if (i < n) {
    int pos = atomicAdd(&base[len[i]], 1);
    order[pos] = i;
  }
}

struct ConvArgs {
  const float* hsrc; const float* hdst;
  const int* nbr; const int* len; const int* ord;
  const uint16_t* Wih; const uint16_t* Whh;   // bf16, k4-interleaved layer slice
  const float* bih; const float* bhh;         // [512]
  const float* Wself; const float* Wneigh;    // [128,128]
  const float* bvec;                          // [128]
  const float* gamma; const float* beta;      // [128] (item side only)
  float* out;
  int K; int ln; int nblk;
};

// one block = 8 destination nodes; 256 threads: d = tid&127, half = tid>>7 owns 4 nodes
__global__ __launch_bounds__(256)
void layer_k(ConvArgs targ, ConvArgs iarg) {
  const bool is_tag = ((int)blockIdx.x < targ.nblk);
  const ConvArgs& a = is_tag ? targ : iarg;
  const int blk  = is_tag ? (int)blockIdx.x : ((int)blockIdx.x - targ.nblk);
  const int tid  = threadIdx.x;
  const int d    = tid & 127;
  const int half = tid >> 7;
  const int n0   = blk * 8;
  const int K    = a.K;

  __shared__ __align__(16) float xs[8][HD];
  __shared__ __align__(16) float hs[8][HD];
  __shared__ int lens_s[8];
  __shared__ int ids_s[8];

  if (tid < 8) {
    int id = a.ord[n0 + tid];
    ids_s[tid]  = id;
    lens_s[tid] = a.len[id];
  }
  hs[half * 4 + 0][d] = 0.f; hs[half * 4 + 1][d] = 0.f;
  hs[half * 4 + 2][d] = 0.f; hs[half * 4 + 3][d] = 0.f;
  __syncthreads();

  int lenr[4];
  #pragma unroll
  for (int j = 0; j < 4; j++) lenr[j] = lens_s[half * 4 + j];
  int tmax = lens_s[0];
  #pragma unroll
  for (int b = 1; b < 8; b++) tmax = (lens_s[b] > tmax) ? lens_s[b] : tmax;

  const float bi0 = a.bih[d]       + a.bhh[d];
  const float bf0 = a.bih[128 + d] + a.bhh[128 + d];
  const float bg0 = a.bih[256 + d] + a.bhh[256 + d];
  const float bo0 = a.bih[384 + d] + a.bhh[384 + d];

  // interleaved layout: uint2 index = k4*512 + gate*128 + d  (coalesced across lanes)
  const uint2* WI = reinterpret_cast<const uint2*>(a.Wih);
  const uint2* WH = reinterpret_cast<const uint2*>(a.Whh);

  float cc[4] = {0.f, 0.f, 0.f, 0.f};

  for (int t = 0; t < tmax; ++t) {
    { // gather x_t: 256 threads cover 8 rows x 32 float4
      int b = tid >> 5, q = tid & 31;
      if (t < lens_s[b]) {
        int idx = a.nbr[(size_t)ids_s[b] * K + t];
        reinterpret_cast<float4*>(xs[b])[q] =
            reinterpret_cast<const float4*>(a.hsrc + (size_t)idx * HD)[q];
      }
    }
    __syncthreads();

    float g0[4], g1[4], g2[4], g3[4];
    #pragma unroll
    for (int j = 0; j < 4; j++) { g0[j] = bi0; g1[j] = bf0; g2[j] = bg0; g3[j] = bo0; }

    #pragma unroll 4
    for (int k4 = 0; k4 < 32; k4++) {
      const int wb = (k4 << 9) + d;
      const float4 fi0 = unpack_bf4(WI[wb]);
      const float4 fi1 = unpack_bf4(WI[wb + 128]);
      const float4 fi2 = unpack_bf4(WI[wb + 256]);
      const float4 fi3 = unpack_bf4(WI[wb + 384]);
      const float4 fh0 = unpack_bf4(WH[wb]);
      const float4 fh1 = unpack_bf4(WH[wb + 128]);
      const float4 fh2 = unpack_bf4(WH[wb + 256]);
      const float4 fh3 = unpack_bf4(WH[wb + 384]);
      #pragma unroll
      for (int j = 0; j < 4; j++) {
        if (t < lenr[j]) {   // uniform per block-half (and nearly always true after sorting)
          const int b = half * 4 + j;
          const float4 x4 = reinterpret_cast<const float4*>(xs[b])[k4];
          const float4 h4 = reinterpret_cast<const float4*>(hs[b])[k4];
          fma4(g0[j], fi0, x4); fma4(g0[j], fh0, h4);
          fma4(g1[j], fi1, x4); fma4(g1[j], fh1, h4);
          fma4(g2[j], fi2, x4); fma4(g2[j], fh2, h4);
          fma4(g3[j], fi3, x4); fma4(g3[j], fh3, h4);
        }
      }
    }
    __syncthreads();

    #pragma unroll
    for (int j = 0; j < 4; j++) {
      if (t < lenr[j]) {
        const float iv = sigm(g0[j]);
        const float fv = sigm(g1[j]);
        const float gv = tanhft(g2[j]);
        const float ov = sigm(g3[j]);
        const float cn = fmaf(fv, cc[j], iv * gv);
        cc[j] = cn;
        hs[half * 4 + j][d] = ov * tanhft(cn);
      }
    }
    // next gate-read of hs is ordered by the post-gather barrier.
  }

  // ---- epilogue: out = hdst @ Wself^T + hn @ Wneigh^T + b (then optional LN) ----
  {
    int b = tid >> 5, q = tid & 31;
    reinterpret_cast<float4*>(xs[b])[q] =
        reinterpret_cast<const float4*>(a.hdst + (size_t)ids_s[b] * HD)[q];
  }
  __syncthreads();

  float ov[4];
  const float bd = a.bvec[d];
  #pragma unroll
  for (int j = 0; j < 4; j++) ov[j] = bd;

  const float4* wsp = reinterpret_cast<const float4*>(a.Wself  + (size_t)d * HD);
  const float4* wnp = reinterpret_cast<const float4*>(a.Wneigh + (size_t)d * HD);
  #pragma unroll 4
  for (int k4 = 0; k4 < 32; k4++) {
    const float4 aa = wsp[k4], ee = wnp[k4];
    #pragma unroll
    for (int j = 0; j < 4; j++) {
      const int b = half * 4 + j;
      const float4 hd4 = reinterpret_cast<const float4*>(xs[b])[k4];
      const float4 hn4 = reinterpret_cast<const float4*>(hs[b])[k4];
      fma4(ov[j], aa, hd4);
      fma4(ov[j], ee, hn4);
    }
  }

  if (!a.ln) {
    #pragma unroll
    for (int j = 0; j < 4; j++)
      a.out[(size_t)ids_s[half * 4 + j] * HD + d] = ov[j];
  } else {
    __syncthreads();
    #pragma unroll
    for (int j = 0; j < 4; j++) xs[half * 4 + j][d] = ov[j];
    __syncthreads();
    const int b = tid >> 5, l = tid & 31;   // 32 lanes per row
    float s = 0.f, s2 = 0.f;
    float vloc[4];
    #pragma unroll
    for (int q = 0; q < 4; q++) {
      float v = xs[b][l + q * 32];
      vloc[q] = v; s += v; s2 += v * v;
    }
    #pragma unroll
    for (int off = 16; off >= 1; off >>= 1) {
      s  += __shfl_xor(s,  off);
      s2 += __shfl_xor(s2, off);
    }
    const float mu   = s  * (1.f / 128.f);
    const float var  = s2 * (1.f / 128.f) - mu * mu;
    const float istd = rsqrtf(var + 1e-5f);
    #pragma unroll
    for (int q = 0; q < 4; q++) {
      const int dd = l + q * 32;
      a.out[(size_t)ids_s[b] * HD + dd] =
          (vloc[q] - mu) * istd * a.gamma[dd] + a.beta[dd];
    }
  }
}

__global__ __launch_bounds__(128)
void final_k(const float* __restrict__ hi, const int* __restrict__ inv,
             const float* __restrict__ Wf, float* __restrict__ out) {
  __shared__ __align__(16) float row[HD];
  const int i  = blockIdx.x;
  const int dd = threadIdx.x;
  const int r  = inv[i];
  row[dd] = hi[(size_t)r * HD + dd];
  __syncthreads();
  float acc = 0.f;
  const float4* w  = reinterpret_cast<const float4*>(Wf + (size_t)dd * HD);
  const float4* rr = reinterpret_cast<const float4*>(row);
  #pragma unroll 8
  for (int k4 = 0; k4 < 32; k4++) fma4(acc, w[k4], rr[k4]);
  out[(size_t)i * HD + dd] = (acc > 0.f) ? acc : 0.01f * acc;
}

} // namespace

extern "C" void kernel_launch(void* const* d_in, const int* in_sizes, int n_in,
                              void* d_out, int out_size, void* d_ws, size_t ws_size,
                              hipStream_t stream) {
  (void)in_sizes; (void)n_in; (void)out_size; (void)ws_size;

  const int*   items      = (const int*)d_in[0];
  const int*   nbr_item   = (const int*)d_in[1];
  const int*   len_tag    = (const int*)d_in[2];
  const int*   nbr_tag    = (const int*)d_in[3];
  const int*   len_item   = (const int*)d_in[4];
  const float* item_table = (const float*)d_in[5];
  const float* tag_table  = (const float*)d_in[6];
  const float* Wih_as   = (const float*)d_in[7];
  const float* Whh_as   = (const float*)d_in[8];
  const float* bih_as   = (const float*)d_in[9];
  const float* bhh_as   = (const float*)d_in[10];
  const float* Wself_as  = (const float*)d_in[11];
  const float* Wneigh_as = (const float*)d_in[12];
  const float* b_as      = (const float*)d_in[13];
  const float* Wih_ras   = (const float*)d_in[14];
  const float* Whh_ras   = (const float*)d_in[15];
  const float* bih_ras   = (const float*)d_in[16];
  const float* bhh_ras   = (const float*)d_in[17];
  const float* Wself_ras  = (const float*)d_in[18];
  const float* Wneigh_ras = (const float*)d_in[19];
  const float* b_ras      = (const float*)d_in[20];
  const float* ln_gamma = (const float*)d_in[21];
  const float* ln_beta  = (const float*)d_in[22];
  const float* W_final  = (const float*)d_in[23];
  float* out = (float*)d_out;

  char* p = (char*)d_ws;
  auto take = [&](size_t bytes) -> char* {
    char* r = p;
    p += (bytes + 255) & ~(size_t)255;
    return r;
  };
  int* present = (int*)take((size_t)VOCAB * sizeof(int));
  int* rank    = (int*)take((size_t)(VOCAB + 1) * sizeof(int));
  int* invp    = (int*)take((size_t)N_ITEMS * sizeof(int));
  float* hiA = (float*)take((size_t)N_ITEMS * HD * sizeof(float));
  float* hiB = (float*)take((size_t)N_ITEMS * HD * sizeof(float));
  float* htA = (float*)take((size_t)N_TAGS * HD * sizeof(float));
  float* htB = (float*)take((size_t)N_TAGS * HD * sizeof(float));
  const int WSZ = NLAYER * 512 * HD;   // 262144 per tensor
  uint16_t* WihA = (uint16_t*)take((size_t)WSZ * 2);
  uint16_t* WhhA = (uint16_t*)take((size_t)WSZ * 2);
  uint16_t* WihR = (uint16_t*)take((size_t)WSZ * 2);
  uint16_t* WhhR = (uint16_t*)take((size_t)WSZ * 2);
  int* hists = (int*)take((size_t)(KTAG + 1 + KITEM + 1) * sizeof(int));  // 42 ints, zeroed
  int* hist_tag  = hists;            // [33]
  int* hist_item = hists + KTAG + 1; // [9]
  int* base_tag  = (int*)take((size_t)(KTAG + 1) * sizeof(int));
  int* base_item = (int*)take((size_t)(KITEM + 1) * sizeof(int));
  int* ord_tag   = (int*)take((size_t)N_TAGS * sizeof(int));
  int* ord_item  = (int*)take((size_t)N_ITEMS * sizeof(int));

  zero_i32<<<(VOCAB + 255) / 256, 256, 0, stream>>>(present, VOCAB);
  zero_i32<<<1, 64, 0, stream>>>(hists, KTAG + 1 + KITEM + 1);
  mark_k<<<(N_ITEMS + 255) / 256, 256, 0, stream>>>(items, present);
  scan_k<<<1, 1024, 0, stream>>>(present, rank);
  build_k<<<(VOCAB * 32 + 255) / 256, 256, 0, stream>>>(present, rank, item_table, hiA);
  pad_k<<<(N_ITEMS * 32 + 255) / 256, 256, 0, stream>>>(rank, item_table, hiA);
  inv_k<<<(N_ITEMS + 255) / 256, 256, 0, stream>>>(items, rank, invp);
  tobf16_il_k<<<(WSZ + 255) / 256, 256, 0, stream>>>(Wih_as, WihA, WSZ);
  tobf16_il_k<<<(WSZ + 255) / 256, 256, 0, stream>>>(Whh_as, WhhA, WSZ);
  tobf16_il_k<<<(WSZ + 255) / 256, 256, 0, stream>>>(Wih_ras, WihR, WSZ);
  tobf16_il_k<<<(WSZ + 255) / 256, 256, 0, stream>>>(Whh_ras, WhhR, WSZ);
  hist_k<<<(N_TAGS + 255) / 256, 256, 0, stream>>>(len_tag, N_TAGS, hist_tag);
  hist_k<<<(N_ITEMS + 255) / 256, 256, 0, stream>>>(len_item, N_ITEMS, hist_item);
  base_k<<<1, 64, 0, stream>>>(hist_tag, base_tag, hist_item, base_item);
  scatter_k<<<(N_TAGS + 255) / 256, 256, 0, stream>>>(len_tag, N_TAGS, base_tag, ord_tag);
  scatter_k<<<(N_ITEMS + 255) / 256, 256, 0, stream>>>(len_item, N_ITEMS, base_item, ord_item);

  const float* hi_cur = hiA; float* hi_nxt = hiB;
  const float* ht_cur = tag_table; float* ht_nxt = htA;

  for (int l = 0; l < NLAYER; ++l) {
    ConvArgs ta, ia;
    ta.hsrc = hi_cur; ta.hdst = ht_cur;
    ta.nbr = nbr_item; ta.len = len_tag; ta.ord = ord_tag;
    ta.Wih = WihA + (size_t)l * 512 * HD; ta.Whh = WhhA + (size_t)l * 512 * HD;
    ta.bih = bih_as + (size_t)l * 512;    ta.bhh = bhh_as + (size_t)l * 512;
    ta.Wself = Wself_as + (size_t)l * HD * HD; ta.Wneigh = Wneigh_as + (size_t)l * HD * HD;
    ta.bvec = b_as + (size_t)l * HD;
    ta.gamma = nullptr; ta.beta = nullptr;
    ta.out = ht_nxt; ta.K = KTAG; ta.ln = 0; ta.nblk = N_TAGS / 8;

    ia.hsrc = ht_cur; ia.hdst = hi_cur;
    ia.nbr = nbr_tag; ia.len = len_item; ia.ord = ord_item;
    ia.Wih = WihR + (size_t)l * 512 * HD; ia.Whh = WhhR + (size_t)l * 512 * HD;
    ia.bih = bih_ras + (size_t)l * 512;   ia.bhh = bhh_ras + (size_t)l * 512;
    ia.Wself = Wself_ras + (size_t)l * HD * HD; ia.Wneigh = Wneigh_ras + (size_t)l * HD * HD;
    ia.bvec = b_ras + (size_t)l * HD;
    ia.gamma = ln_gamma + (size_t)l * HD; ia.beta = ln_beta + (size_t)l * HD;
    ia.out = hi_nxt; ia.K = KITEM; ia.ln = 1; ia.nblk = N_ITEMS / 8;

    layer_k<<<ta.nblk + ia.nblk, 256, 0, stream>>>(ta, ia);

    hi_cur = hi_nxt; hi_nxt = (hi_cur == hiA) ? hiB : hiA;
    ht_cur = ht_nxt; ht_nxt = (ht_cur == htA) ? htB : htA;
  }

  final_k<<<N_ITEMS, 128, 0, stream>>>(hi_cur, invp, W_final, out);
}

// Round 3
// 603.691 us; speedup vs baseline: 25.3803x; 5.0005x over previous
//
#include <hip/hip_runtime.h>
#include <cstdint>
#include <cstddef>

namespace {

constexpr int N_ITEMS = 10000;
constexpr int N_TAGS  = 2000;
constexpr int VOCAB   = 50000;
constexpr int KTAG    = 32;
constexpr int KITEM   = 8;
constexpr int HD      = 128;
constexpr int NLAYER  = 4;

using bfrag = __attribute__((ext_vector_type(8))) short;
using f32x4 = __attribute__((ext_vector_type(4))) float;

__device__ __forceinline__ float sigm(float x)   { return 1.0f / (1.0f + __expf(-x)); }
__device__ __forceinline__ float tanhft(float x) { return 1.0f - 2.0f / (1.0f + __expf(2.0f * x)); }

__device__ __forceinline__ uint16_t f2bf(float f) {
  uint32_t u = __float_as_uint(f);
  u += 0x7fffu + ((u >> 16) & 1u);   // RNE
  return (uint16_t)(u >> 16);
}

__global__ void zero_i32(int* p, int n) {
  int i = blockIdx.x * blockDim.x + threadIdx.x;
  if (i < n) p[i] = 0;
}

__global__ void mark_k(const int* __restrict__ items, int* __restrict__ present) {
  int i = blockIdx.x * blockDim.x + threadIdx.x;
  if (i < N_ITEMS) present[items[i]] = 1;
}

__global__ __launch_bounds__(1024) void scan_k(const int* __restrict__ present,
                                               int* __restrict__ rank) {
  __shared__ int tmp[1024];
  const int tid  = threadIdx.x;
  const int CH   = 49;
  const int base = tid * CH;
  int s = 0;
  for (int j = 0; j < CH; j++) { int idx = base + j; if (idx < VOCAB) s += present[idx]; }
  tmp[tid] = s;
  __syncthreads();
  for (int off = 1; off < 1024; off <<= 1) {
    int v = (tid >= off) ? tmp[tid - off] : 0;
    __syncthreads();
    tmp[tid] += v;
    __syncthreads();
  }
  int run = tmp[tid] - s;
  for (int j = 0; j < CH; j++) {
    int idx = base + j;
    if (idx < VOCAB) { rank[idx] = run; run += present[idx]; }
  }
  if (tid == 1023) rank[VOCAB] = run;
}

__global__ void build_k(const int* __restrict__ present, const int* __restrict__ rank,
                        const float* __restrict__ table, float* __restrict__ hi) {
  int gid = blockIdx.x * blockDim.x + threadIdx.x;
  if (gid >= VOCAB * 32) return;
  int v = gid >> 5, q = gid & 31;
  if (present[v]) {
    int slot = rank[v];
    reinterpret_cast<float4*>(hi + (size_t)slot * HD)[q] =
        reinterpret_cast<const float4*>(table + (size_t)v * HD)[q];
  }
}

__global__ void pad_k(const int* __restrict__ rank, const float* __restrict__ table,
                      float* __restrict__ hi) {
  int gid = blockIdx.x * blockDim.x + threadIdx.x;
  if (gid >= N_ITEMS * 32) return;
  int slot = gid >> 5, q = gid & 31;
  if (slot >= rank[VOCAB]) {
    reinterpret_cast<float4*>(hi + (size_t)slot * HD)[q] =
        reinterpret_cast<const float4*>(table)[q];
  }
}

__global__ void inv_k(const int* __restrict__ items, const int* __restrict__ rank,
                      int* __restrict__ inv) {
  int i = blockIdx.x * blockDim.x + threadIdx.x;
  if (i < N_ITEMS) inv[i] = rank[items[i]];
}

// Gate weights -> MFMA B-fragment order.
// out flat: [layer][w:3][g:2][s:3][lane:6][j:3]  (bf16)
// B[k][col]: k = s*32 + (lane>>4)*8 + j, col = g*128 + w*16 + (lane&15)
// k<128 -> Wih[col][k], else Whh[col][k-128]
__global__ void convW_gate_k(const float* __restrict__ Wih, const float* __restrict__ Whh,
                             uint16_t* __restrict__ out, int total) {
  int o = blockIdx.x * blockDim.x + threadIdx.x;
  if (o >= total) return;
  int j = o & 7, lane = (o >> 3) & 63, s = (o >> 9) & 7, g = (o >> 12) & 3, w = (o >> 14) & 7, l = o >> 17;
  int k = s * 32 + ((lane >> 4) << 3) + j;
  int c = g * 128 + w * 16 + (lane & 15);
  float v = (k < 128) ? Wih[((size_t)l * 512 + c) * 128 + k]
                      : Whh[((size_t)l * 512 + c) * 128 + (k - 128)];
  out[o] = f2bf(v);
}

// Epilogue weights: out[layer][w:3][s:3][lane:6][j:3];
// B[k][col]: col = w*16+(lane&15); k<128 -> Wself[col][k], else Wneigh[col][k-128]
__global__ void convW_ep_k(const float* __restrict__ Wself, const float* __restrict__ Wneigh,
                           uint16_t* __restrict__ out, int total) {
  int o = blockIdx.x * blockDim.x + threadIdx.x;
  if (o >= total) return;
  int j = o & 7, lane = (o >> 3) & 63, s = (o >> 9) & 7, w = (o >> 12) & 7, l = o >> 15;
  int k = s * 32 + ((lane >> 4) << 3) + j;
  int c = w * 16 + (lane & 15);
  float v = (k < 128) ? Wself[((size_t)l * 128 + c) * 128 + k]
                      : Wneigh[((size_t)l * 128 + c) * 128 + (k - 128)];
  out[o] = f2bf(v);
}

// ---- length bucketing (counting sort, descending length) ----
__global__ void hist_k(const int* __restrict__ len, int n, int* __restrict__ hist) {
  int i = blockIdx.x * blockDim.x + threadIdx.x;
  if (i < n) atomicAdd(&hist[len[i]], 1);
}

__global__ void base_k(const int* __restrict__ hist_tag, int* __restrict__ base_tag,
                       const int* __restrict__ hist_item, int* __restrict__ base_item) {
  if (threadIdx.x == 0) {
    int acc = 0;
    for (int l = KTAG; l >= 1; --l) { base_tag[l] = acc; acc += hist_tag[l]; }
    acc = 0;
    for (int l = KITEM; l >= 1; --l) { base_item[l] = acc; acc += hist_item[l]; }
  }
}

__global__ void scatter_k(const int* __restrict__ len, int n, int* __restrict__ base,
                          int* __restrict__ order) {
  int i = blockIdx.x * blockDim.x + threadIdx.x;
  if (i < n) {
    int pos = atomicAdd(&base[len[i]], 1);
    order[pos] = i;
  }
}

struct ConvArgs2 {
  const float* hsrc; const float* hdst;
  const int* nbr; const int* len; const int* ord;
  const uint16_t* Wg;   // gate B frags, layer slice (131072 u16)
  const uint16_t* We;   // epilogue B frags, layer slice (32768 u16)
  const float* bih; const float* bhh; const float* bvec;
  const float* gamma; const float* beta;
  float* out;
  int K; int ln; int nblk;
};

// Block = 16 dst nodes, 8 waves. Wave w owns dims [16w,16w+16) for all 4 gates.
// A (bf16, LDS, XOR-swizzled ^((row&7)<<4) bytes) = [x_t | h], K=256.
// B frags in VGPRs for whole kernel. State update fully lane-local.
__global__ __launch_bounds__(512, 2)
void layer2_k(ConvArgs2 targ, ConvArgs2 iarg) {
  const bool is_tag = ((int)blockIdx.x < targ.nblk);
  const ConvArgs2& a = is_tag ? targ : iarg;
  const int blk  = is_tag ? (int)blockIdx.x : ((int)blockIdx.x - targ.nblk);
  const int tid  = threadIdx.x;
  const int wv   = tid >> 6;
  const int lane = tid & 63;
  const int n0   = blk * 16;
  const int K    = a.K;

  __shared__ uint16_t xs[2][2048];   // [buf][node*128 + k] bf16, swizzled
  __shared__ uint16_t hs[2048];      // [node*128 + k] bf16, swizzled
  __shared__ float    os[16][128];
  __shared__ int ids_s[16], lens_s[16];

  if (tid < 16) {
    int id = a.ord[n0 + tid];
    ids_s[tid]  = id;
    lens_s[tid] = a.len[id];
  }
  *reinterpret_cast<ushort4*>(&hs[tid * 4]) = make_ushort4(0, 0, 0, 0);
  __syncthreads();

  // gather roles: 32 threads per node, each a float4 of the feature row
  const int pnode = tid >> 5, pq = tid & 31;
  const int pid   = ids_s[pnode];
  const int plen  = lens_s[pnode];
  const int pidx  = (pnode * 128 + pq * 4) ^ ((pnode & 7) << 3);   // u16 units

  const int row = lane & 15;                 // A row / out node-subindex
  const int myd = wv * 16 + row;             // this lane's output dim (as col)
  const int nb  = (lane >> 4) * 4;           // node base for acc rows
  int lr[4];
  #pragma unroll
  for (int r = 0; r < 4; r++) lr[r] = lens_s[nb + r];
  int tmax = 1;
  for (int b = 0; b < 16; b++) tmax = max(tmax, lens_s[b]);

  // gate-B fragments: 32 x 16B = 128 VGPRs, resident across all steps
  bfrag Bg[4][8];
  #pragma unroll
  for (int g = 0; g < 4; g++) {
    #pragma unroll
    for (int s = 0; s < 8; s++)
      Bg[g][s] = *reinterpret_cast<const bfrag*>(a.Wg + (size_t)((((wv * 4 + g) * 8 + s) * 64 + lane) * 8));
  }

  float bias[4];
  #pragma unroll
  for (int g = 0; g < 4; g++) bias[g] = a.bih[g * 128 + myd] + a.bhh[g * 128 + myd];

  { // gather x_0 (len >= 1 always)
    int idx = a.nbr[(size_t)pid * K];
    float4 v = *reinterpret_cast<const float4*>(a.hsrc + (size_t)idx * HD + pq * 4);
    *reinterpret_cast<ushort4*>(&xs[0][pidx]) = make_ushort4(f2bf(v.x), f2bf(v.y), f2bf(v.z), f2bf(v.w));
  }
  __syncthreads();

  float cst[4] = {0.f, 0.f, 0.f, 0.f};

  for (int t = 0; t < tmax; ++t) {
    const int cur = t & 1;
    // prefetch x_{t+1} into registers (latency hidden under MFMA)
    float4 pv; bool pact = false;
    if (t + 1 < tmax && t + 1 < plen) {
      int idx = a.nbr[(size_t)pid * K + t + 1];
      pv = *reinterpret_cast<const float4*>(a.hsrc + (size_t)idx * HD + pq * 4);
      pact = true;
    }

    f32x4 C[4];
    #pragma unroll
    for (int g = 0; g < 4; g++) { f32x4 c0 = {bias[g], bias[g], bias[g], bias[g]}; C[g] = c0; }

    #pragma unroll
    for (int s = 0; s < 8; s++) {
      const uint16_t* areg = (s < 4) ? &xs[cur][0] : &hs[0];
      const int koff = (s & 3) * 32 + ((lane >> 4) << 3);
      bfrag af = *reinterpret_cast<const bfrag*>(&areg[(row * 128 + koff) ^ ((row & 7) << 3)]);
      #pragma unroll
      for (int g = 0; g < 4; g++)
        C[g] = __builtin_amdgcn_mfma_f32_16x16x32_bf16(af, Bg[g][s], C[g], 0, 0, 0);
    }

    float hv[4];
    #pragma unroll
    for (int r = 0; r < 4; r++) {
      if (t < lr[r]) {
        const float iv = sigm(C[0][r]);
        const float fv = sigm(C[1][r]);
        const float gv = tanhft(C[2][r]);
        const float o  = sigm(C[3][r]);
        const float cn = fmaf(fv, cst[r], iv * gv);
        cst[r] = cn;
        hv[r]  = o * tanhft(cn);
      }
    }
    __syncthreads();   // all A reads (xs[cur], hs) done
    if (pact)
      *reinterpret_cast<ushort4*>(&xs[cur ^ 1][pidx]) =
          make_ushort4(f2bf(pv.x), f2bf(pv.y), f2bf(pv.z), f2bf(pv.w));
    #pragma unroll
    for (int r = 0; r < 4; r++)
      if (t < lr[r])
        hs[((nb + r) * 128 + myd) ^ (((nb + r) & 7) << 3)] = f2bf(hv[r]);
    __syncthreads();   // writes visible for next step
  }

  // ---- epilogue: out = hdst@Wself^T + hn@Wneigh^T + b (+LN for items) ----
  bfrag Be[8];
  #pragma unroll
  for (int s = 0; s < 8; s++)
    Be[s] = *reinterpret_cast<const bfrag*>(a.We + (size_t)(((wv * 8 + s) * 64 + lane) * 8));

  { // gather hdst into xs[0]
    float4 v = *reinterpret_cast<const float4*>(a.hdst + (size_t)pid * HD + pq * 4);
    *reinterpret_cast<ushort4*>(&xs[0][pidx]) = make_ushort4(f2bf(v.x), f2bf(v.y), f2bf(v.z), f2bf(v.w));
  }
  __syncthreads();

  f32x4 O;
  { float bv = a.bvec[myd]; f32x4 o0 = {bv, bv, bv, bv}; O = o0; }
  #pragma unroll
  for (int s = 0; s < 8; s++) {
    const uint16_t* areg = (s < 4) ? &xs[0][0] : &hs[0];
    const int koff = (s & 3) * 32 + ((lane >> 4) << 3);
    bfrag af = *reinterpret_cast<const bfrag*>(&areg[(row * 128 + koff) ^ ((row & 7) << 3)]);
    O = __builtin_amdgcn_mfma_f32_16x16x32_bf16(af, Be[s], O, 0, 0, 0);
  }

  if (!a.ln) {
    #pragma unroll
    for (int r = 0; r < 4; r++)
      a.out[(size_t)ids_s[nb + r] * HD + myd] = O[r];
  } else {
    #pragma unroll
    for (int r = 0; r < 4; r++) os[nb + r][myd] = O[r];
    __syncthreads();
    const int node = tid >> 5, l = tid & 31;
    float s1 = 0.f, s2 = 0.f, vl[4];
    #pragma unroll
    for (int q = 0; q < 4; q++) {
      float v = os[node][l + q * 32];
      vl[q] = v; s1 += v; s2 += v * v;
    }
    #pragma unroll
    for (int off = 16; off >= 1; off >>= 1) {
      s1 += __shfl_xor(s1, off);
      s2 += __shfl_xor(s2, off);
    }
    const float mu   = s1 * (1.f / 128.f);
    const float var  = s2 * (1.f / 128.f) - mu * mu;
    const float istd = rsqrtf(var + 1e-5f);
    const int oid = ids_s[node];
    #pragma unroll
    for (int q = 0; q < 4; q++) {
      int dd = l + q * 32;
      a.out[(size_t)oid * HD + dd] = (vl[q] - mu) * istd * a.gamma[dd] + a.beta[dd];
    }
  }
}

__global__ __launch_bounds__(128)
void final_k(const float* __restrict__ hi, const int* __restrict__ inv,
             const float* __restrict__ Wf, float* __restrict__ out) {
  __shared__ __align__(16) float rowbuf[HD];
  const int i  = blockIdx.x;
  const int dd = threadIdx.x;
  const int r  = inv[i];
  rowbuf[dd] = hi[(size_t)r * HD + dd];
  __syncthreads();
  float acc = 0.f;
  const float4* w  = reinterpret_cast<const float4*>(Wf + (size_t)dd * HD);
  const float4* rr = reinterpret_cast<const float4*>(rowbuf);
  #pragma unroll 8
  for (int k4 = 0; k4 < 32; k4++) {
    float4 a = w[k4], b = rr[k4];
    acc = fmaf(a.x, b.x, acc); acc = fmaf(a.y, b.y, acc);
    acc = fmaf(a.z, b.z, acc); acc = fmaf(a.w, b.w, acc);
  }
  out[(size_t)i * HD + dd] = (acc > 0.f) ? acc : 0.01f * acc;
}

} // namespace

extern "C" void kernel_launch(void* const* d_in, const int* in_sizes, int n_in,
                              void* d_out, int out_size, void* d_ws, size_t ws_size,
                              hipStream_t stream) {
  (void)in_sizes; (void)n_in; (void)out_size; (void)ws_size;

  const int*   items      = (const int*)d_in[0];
  const int*   nbr_item   = (const int*)d_in[1];
  const int*   len_tag    = (const int*)d_in[2];
  const int*   nbr_tag    = (const int*)d_in[3];
  const int*   len_item   = (const int*)d_in[4];
  const float* item_table = (const float*)d_in[5];
  const float* tag_table  = (const float*)d_in[6];
  const float* Wih_as   = (const float*)d_in[7];
  const float* Whh_as   = (const float*)d_in[8];
  const float* bih_as   = (const float*)d_in[9];
  const float* bhh_as   = (const float*)d_in[10];
  const float* Wself_as  = (const float*)d_in[11];
  const float* Wneigh_as = (const float*)d_in[12];
  const float* b_as      = (const float*)d_in[13];
  const float* Wih_ras   = (const float*)d_in[14];
  const float* Whh_ras   = (const float*)d_in[15];
  const float* bih_ras   = (const float*)d_in[16];
  const float* bhh_ras   = (const float*)d_in[17];
  const float* Wself_ras  = (const float*)d_in[18];
  const float* Wneigh_ras = (const float*)d_in[19];
  const float* b_ras      = (const float*)d_in[20];
  const float* ln_gamma = (const float*)d_in[21];
  const float* ln_beta  = (const float*)d_in[22];
  const float* W_final  = (const float*)d_in[23];
  float* out = (float*)d_out;

  char* p = (char*)d_ws;
  auto take = [&](size_t bytes) -> char* {
    char* r = p;
    p += (bytes + 255) & ~(size_t)255;
    return r;
  };
  int* present = (int*)take((size_t)VOCAB * sizeof(int));
  int* rank    = (int*)take((size_t)(VOCAB + 1) * sizeof(int));
  int* invp    = (int*)take((size_t)N_ITEMS * sizeof(int));
  float* hiA = (float*)take((size_t)N_ITEMS * HD * sizeof(float));
  float* hiB = (float*)take((size_t)N_ITEMS * HD * sizeof(float));
  float* htA = (float*)take((size_t)N_TAGS * HD * sizeof(float));
  float* htB = (float*)take((size_t)N_TAGS * HD * sizeof(float));
  const int GWSZ = NLAYER * 131072;   // gate frag tensor per etype (u16)
  const int EWSZ = NLAYER * 32768;    // epilogue frag tensor per etype (u16)
  uint16_t* WgA = (uint16_t*)take((size_t)GWSZ * 2);
  uint16_t* WgR = (uint16_t*)take((size_t)GWSZ * 2);
  uint16_t* WeA = (uint16_t*)take((size_t)EWSZ * 2);
  uint16_t* WeR = (uint16_t*)take((size_t)EWSZ * 2);
  int* hists = (int*)take((size_t)(KTAG + 1 + KITEM + 1) * sizeof(int));
  int* hist_tag  = hists;
  int* hist_item = hists + KTAG + 1;
  int* base_tag  = (int*)take((size_t)(KTAG + 1) * sizeof(int));
  int* base_item = (int*)take((size_t)(KITEM + 1) * sizeof(int));
  int* ord_tag   = (int*)take((size_t)N_TAGS * sizeof(int));
  int* ord_item  = (int*)take((size_t)N_ITEMS * sizeof(int));

  zero_i32<<<(VOCAB + 255) / 256, 256, 0, stream>>>(present, VOCAB);
  zero_i32<<<1, 64, 0, stream>>>(hists, KTAG + 1 + KITEM + 1);
  mark_k<<<(N_ITEMS + 255) / 256, 256, 0, stream>>>(items, present);
  scan_k<<<1, 1024, 0, stream>>>(present, rank);
  build_k<<<(VOCAB * 32 + 255) / 256, 256, 0, stream>>>(present, rank, item_table, hiA);
  pad_k<<<(N_ITEMS * 32 + 255) / 256, 256, 0, stream>>>(rank, item_table, hiA);
  inv_k<<<(N_ITEMS + 255) / 256, 256, 0, stream>>>(items, rank, invp);
  convW_gate_k<<<(GWSZ + 255) / 256, 256, 0, stream>>>(Wih_as, Whh_as, WgA, GWSZ);
  convW_gate_k<<<(GWSZ + 255) / 256, 256, 0, stream>>>(Wih_ras, Whh_ras, WgR, GWSZ);
  convW_ep_k<<<(EWSZ + 255) / 256, 256, 0, stream>>>(Wself_as, Wneigh_as, WeA, EWSZ);
  convW_ep_k<<<(EWSZ + 255) / 256, 256, 0, stream>>>(Wself_ras, Wneigh_ras, WeR, EWSZ);
  hist_k<<<(N_TAGS + 255) / 256, 256, 0, stream>>>(len_tag, N_TAGS, hist_tag);
  hist_k<<<(N_ITEMS + 255) / 256, 256, 0, stream>>>(len_item, N_ITEMS, hist_item);
  base_k<<<1, 64, 0, stream>>>(hist_tag, base_tag, hist_item, base_item);
  scatter_k<<<(N_TAGS + 255) / 256, 256, 0, stream>>>(len_tag, N_TAGS, base_tag, ord_tag);
  scatter_k<<<(N_ITEMS + 255) / 256, 256, 0, stream>>>(len_item, N_ITEMS, base_item, ord_item);

  const float* hi_cur = hiA; float* hi_nxt = hiB;
  const float* ht_cur = tag_table; float* ht_nxt = htA;

  for (int l = 0; l < NLAYER; ++l) {
    ConvArgs2 ta, ia;
    ta.hsrc = hi_cur; ta.hdst = ht_cur;
    ta.nbr = nbr_item; ta.len = len_tag; ta.ord = ord_tag;
    ta.Wg = WgA + (size_t)l * 131072; ta.We = WeA + (size_t)l * 32768;
    ta.bih = bih_as + (size_t)l * 512; ta.bhh = bhh_as + (size_t)l * 512;
    ta.bvec = b_as + (size_t)l * HD;
    ta.gamma = nullptr; ta.beta = nullptr;
    ta.out = ht_nxt; ta.K = KTAG; ta.ln = 0; ta.nblk = N_TAGS / 16;

    ia.hsrc = ht_cur; ia.hdst = hi_cur;
    ia.nbr = nbr_tag; ia.len = len_item; ia.ord = ord_item;
    ia.Wg = WgR + (size_t)l * 131072; ia.We = WeR + (size_t)l * 32768;
    ia.bih = bih_ras + (size_t)l * 512; ia.bhh = bhh_ras + (size_t)l * 512;
    ia.bvec = b_ras + (size_t)l * HD;
    ia.gamma = ln_gamma + (size_t)l * HD; ia.beta = ln_beta + (size_t)l * HD;
    ia.out = hi_nxt; ia.K = KITEM; ia.ln = 1; ia.nblk = N_ITEMS / 16;

    layer2_k<<<ta.nblk + ia.nblk, 512, 0, stream>>>(ta, ia);

    hi_cur = hi_nxt; hi_nxt = (hi_cur == hiA) ? hiB : hiA;
    ht_cur = ht_nxt; ht_nxt = (ht_cur == htA) ? htB : htA;
  }

  final_k<<<N_ITEMS, 128, 0, stream>>>(hi_cur, invp, W_final, out);
}

// Round 4
// 487.027 us; speedup vs baseline: 31.4600x; 1.2395x over previous
//
#include <hip/hip_runtime.h>
#include <cstdint>
#include <cstddef>

namespace {

constexpr int N_ITEMS = 10000;
constexpr int N_TAGS  = 2000;
constexpr int VOCAB   = 50000;
constexpr int KTAG    = 32;
constexpr int KITEM   = 8;
constexpr int HD      = 128;
constexpr int NLAYER  = 4;
constexpr int GWSZ = NLAYER * 131072;   // gate frag elems per etype
constexpr int EWSZ = NLAYER * 32768;    // epilogue frag elems per etype

using bfrag = __attribute__((ext_vector_type(8))) short;
using f32x4 = __attribute__((ext_vector_type(4))) float;

__device__ __forceinline__ float sigm(float x)   { return 1.0f / (1.0f + __expf(-x)); }
__device__ __forceinline__ float tanhft(float x) { return 1.0f - 2.0f / (1.0f + __expf(2.0f * x)); }

__device__ __forceinline__ uint16_t f2bf(float f) {
  uint32_t u = __float_as_uint(f);
  u += 0x7fffu + ((u >> 16) & 1u);   // RNE
  return (uint16_t)(u >> 16);
}

__global__ void zero_k(int* present, int* hists, int nh) {
  int i = blockIdx.x * blockDim.x + threadIdx.x;
  if (i < VOCAB) present[i] = 0;
  else if (i - VOCAB < nh) hists[i - VOCAB] = 0;
}

__global__ void mark_k(const int* __restrict__ items, int* __restrict__ present) {
  int i = blockIdx.x * blockDim.x + threadIdx.x;
  if (i < N_ITEMS) present[items[i]] = 1;
}

// ---- 3-phase multi-block scan: 49 blocks x 1024 elems ----
__global__ __launch_bounds__(256) void scanA_k(const int* __restrict__ present,
                                               int* __restrict__ partial) {
  __shared__ int ws[4];
  const int b = blockIdx.x, tid = threadIdx.x;
  const int base = b * 1024 + tid * 4;
  int s = 0;
  if (base < VOCAB) {   // VOCAB % 4 == 0
    int4 v = *reinterpret_cast<const int4*>(present + base);
    s = v.x + v.y + v.z + v.w;
  }
  const int lane = tid & 63, wv = tid >> 6;
  #pragma unroll
  for (int off = 32; off >= 1; off >>= 1) s += __shfl_down(s, off);
  if (lane == 0) ws[wv] = s;
  __syncthreads();
  if (tid == 0) partial[b] = ws[0] + ws[1] + ws[2] + ws[3];
}

__global__ void scanB_k(int* __restrict__ partial, int* __restrict__ rank, int nb) {
  const int lane = threadIdx.x;   // 64 threads, single wave
  int v = (lane < nb) ? partial[lane] : 0;
  int sc = v;
  #pragma unroll
  for (int off = 1; off < 64; off <<= 1) {
    int u = __shfl_up(sc, off);
    if (lane >= off) sc += u;
  }
  if (lane < nb) partial[lane] = sc - v;      // exclusive
  if (lane == nb - 1) rank[VOCAB] = sc;       // total
}

__global__ __launch_bounds__(256) void scanC_k(const int* __restrict__ present,
                                               const int* __restrict__ partial,
                                               int* __restrict__ rank) {
  __shared__ int ws[4];
  const int b = blockIdx.x, tid = threadIdx.x;
  const int base = b * 1024 + tid * 4;
  int4 v = {0, 0, 0, 0};
  if (base < VOCAB) v = *reinterpret_cast<const int4*>(present + base);
  const int s = v.x + v.y + v.z + v.w;
  const int lane = tid & 63, wv = tid >> 6;
  int sc = s;
  #pragma unroll
  for (int off = 1; off < 64; off <<= 1) {
    int u = __shfl_up(sc, off);
    if (lane >= off) sc += u;
  }
  if (lane == 63) ws[wv] = sc;
  __syncthreads();
  int woff = partial[b];
  for (int w = 0; w < wv; w++) woff += ws[w];
  const int excl = woff + sc - s;
  if (base < VOCAB) {
    int4 r;
    r.x = excl; r.y = excl + v.x; r.z = excl + v.x + v.y; r.w = excl + v.x + v.y + v.z;
    *reinterpret_cast<int4*>(rank + base) = r;
  }
}

// build (compact rows) + pad (fill_value=0 -> table[0]) + inv, fused
__global__ void bpi_k(const int* __restrict__ present, const int* __restrict__ rank,
                      const int* __restrict__ items, const float* __restrict__ table,
                      float* __restrict__ hi, int* __restrict__ inv) {
  int gid = blockIdx.x * blockDim.x + threadIdx.x;
  if (gid < VOCAB * 32) {
    int v = gid >> 5, q = gid & 31;
    if (present[v]) {
      int slot = rank[v];
      reinterpret_cast<float4*>(hi + (size_t)slot * HD)[q] =
          reinterpret_cast<const float4*>(table + (size_t)v * HD)[q];
    }
  } else if (gid < VOCAB * 32 + N_ITEMS * 32) {
    int g = gid - VOCAB * 32;
    int slot = g >> 5, q = g & 31;
    if (slot >= rank[VOCAB]) {
      reinterpret_cast<float4*>(hi + (size_t)slot * HD)[q] =
          reinterpret_cast<const float4*>(table)[q];
    }
  } else {
    int i = gid - VOCAB * 32 - N_ITEMS * 32;
    if (i < N_ITEMS) inv[i] = rank[items[i]];
  }
}

// All weight->fragment transforms fused.
// Gate out flat: [layer][w:3][g:2][s:3][lane:6][j:3]; B[k][col]:
//   k = s*32+(lane>>4)*8+j, col = g*128+w*16+(lane&15); k<128->Wih else Whh.
// Ep out flat:   [layer][w:3][s:3][lane:6][j:3]; col = w*16+(lane&15); Wself/Wneigh.
__global__ void convW_all_k(const float* __restrict__ WihA, const float* __restrict__ WhhA,
                            const float* __restrict__ WihR, const float* __restrict__ WhhR,
                            const float* __restrict__ WsA,  const float* __restrict__ WnA,
                            const float* __restrict__ WsR,  const float* __restrict__ WnR,
                            uint16_t* __restrict__ GgA, uint16_t* __restrict__ GgR,
                            uint16_t* __restrict__ GeA, uint16_t* __restrict__ GeR) {
  int o = blockIdx.x * blockDim.x + threadIdx.x;
  if (o < 2 * GWSZ) {
    const bool A = (o < GWSZ);
    int oo = A ? o : o - GWSZ;
    const float* Wih = A ? WihA : WihR;
    const float* Whh = A ? WhhA : WhhR;
    uint16_t* outp = A ? GgA : GgR;
    int j = oo & 7, lane = (oo >> 3) & 63, s = (oo >> 9) & 7, g = (oo >> 12) & 3,
        w = (oo >> 14) & 7, l = oo >> 17;
    int k = s * 32 + ((lane >> 4) << 3) + j;
    int c = g * 128 + w * 16 + (lane & 15);
    float v = (k < 128) ? Wih[((size_t)l * 512 + c) * 128 + k]
                        : Whh[((size_t)l * 512 + c) * 128 + (k - 128)];
    outp[oo] = f2bf(v);
  } else if (o < 2 * GWSZ + 2 * EWSZ) {
    int oe = o - 2 * GWSZ;
    const bool A = (oe < EWSZ);
    int oo = A ? oe : oe - EWSZ;
    const float* Ws = A ? WsA : WsR;
    const float* Wn = A ? WnA : WnR;
    uint16_t* outp = A ? GeA : GeR;
    int j = oo & 7, lane = (oo >> 3) & 63, s = (oo >> 9) & 7, w = (oo >> 12) & 7, l = oo >> 15;
    int k = s * 32 + ((lane >> 4) << 3) + j;
    int c = w * 16 + (lane & 15);
    float v = (k < 128) ? Ws[((size_t)l * 128 + c) * 128 + k]
                        : Wn[((size_t)l * 128 + c) * 128 + (k - 128)];
    outp[oo] = f2bf(v);
  }
}

// ---- length bucketing (counting sort, descending) ----
__global__ void hist_all_k(const int* __restrict__ len_tag, const int* __restrict__ len_item,
                           int* __restrict__ hist_tag, int* __restrict__ hist_item) {
  int i = blockIdx.x * blockDim.x + threadIdx.x;
  if (i < N_TAGS) atomicAdd(&hist_tag[len_tag[i]], 1);
  int j = i - N_TAGS;
  if (j >= 0 && j < N_ITEMS) atomicAdd(&hist_item[len_item[j]], 1);
}

__global__ void base_k(const int* __restrict__ hist_tag, int* __restrict__ base_tag,
                       const int* __restrict__ hist_item, int* __restrict__ base_item) {
  if (threadIdx.x == 0) {
    int acc = 0;
    for (int l = KTAG; l >= 1; --l) { base_tag[l] = acc; acc += hist_tag[l]; }
    acc = 0;
    for (int l = KITEM; l >= 1; --l) { base_item[l] = acc; acc += hist_item[l]; }
  }
}

__global__ void scatter_all_k(const int* __restrict__ len_tag, const int* __restrict__ len_item,
                              int* __restrict__ base_tag, int* __restrict__ base_item,
                              int* __restrict__ ord_tag, int* __restrict__ ord_item) {
  int i = blockIdx.x * blockDim.x + threadIdx.x;
  if (i < N_TAGS) {
    int pos = atomicAdd(&base_tag[len_tag[i]], 1);
    ord_tag[pos] = i;
  }
  int j = i - N_TAGS;
  if (j >= 0 && j < N_ITEMS) {
    int pos = atomicAdd(&base_item[len_item[j]], 1);
    ord_item[pos] = j;
  }
}

struct ConvArgs2 {
  const float* hsrc; const float* hdst;
  const int* nbr; const int* len; const int* ord;
  const uint16_t* Wg;   // gate B frags, layer slice
  const uint16_t* We;   // epilogue B frags, layer slice
  const float* bih; const float* bhh; const float* bvec;
  const float* gamma; const float* beta;
  float* out;
  int K; int ln; int nblk;
};

// Block = 16 dst nodes, 8 waves. Wave w owns dims [16w,16w+16) for all 4 gates.
// A (bf16, LDS, XOR-swizzled) = [x_t | h], K=256, fully double-buffered:
// step t reads buf[t&1], writes buf[(t+1)&1]; ONE barrier per step.
__global__ __launch_bounds__(512, 2)
void layer2_k(ConvArgs2 targ, ConvArgs2 iarg) {
  const bool is_tag = ((int)blockIdx.x < targ.nblk);
  const ConvArgs2& a = is_tag ? targ : iarg;
  const int blk  = is_tag ? (int)blockIdx.x : ((int)blockIdx.x - targ.nblk);
  const int tid  = threadIdx.x;
  const int wv   = tid >> 6;
  const int lane = tid & 63;
  const int n0   = blk * 16;
  const int K    = a.K;

  __shared__ uint16_t xs[2][2048];   // [buf][node*128 + k] bf16, swizzled
  __shared__ uint16_t hs[2][2048];
  __shared__ float    os[16][128];
  __shared__ int ids_s[16], lens_s[16];

  if (tid < 16) {
    int id = a.ord[n0 + tid];
    ids_s[tid]  = id;
    lens_s[tid] = a.len[id];
  }
  *reinterpret_cast<ushort4*>(&hs[0][tid * 4]) = make_ushort4(0, 0, 0, 0);
  __syncthreads();

  // gather roles: 32 threads per node, each a float4 of the feature row
  const int pnode = tid >> 5, pq = tid & 31;
  const int pid   = ids_s[pnode];
  const int plen  = lens_s[pnode];
  const int pidx  = (pnode * 128 + pq * 4) ^ ((pnode & 7) << 3);   // u16 units

  const int row = lane & 15;                 // A row / out node-subindex
  const int myd = wv * 16 + row;             // this lane's output dim (col)
  const int nb  = (lane >> 4) * 4;           // node base for acc rows
  int lr[4];
  #pragma unroll
  for (int r = 0; r < 4; r++) lr[r] = lens_s[nb + r];
  int tmax = 1;
  for (int b = 0; b < 16; b++) tmax = max(tmax, lens_s[b]);

  // gate-B fragments: 32 x 16B = 128 VGPRs, resident across all steps
  bfrag Bg[4][8];
  #pragma unroll
  for (int g = 0; g < 4; g++) {
    #pragma unroll
    for (int s = 0; s < 8; s++)
      Bg[g][s] = *reinterpret_cast<const bfrag*>(a.Wg + (size_t)((((wv * 4 + g) * 8 + s) * 64 + lane) * 8));
  }

  float bias[4];
  #pragma unroll
  for (int g = 0; g < 4; g++) bias[g] = a.bih[g * 128 + myd] + a.bhh[g * 128 + myd];

  { // gather x_0 (len >= 1 always)
    int idx = a.nbr[(size_t)pid * K];
    float4 v = *reinterpret_cast<const float4*>(a.hsrc + (size_t)idx * HD + pq * 4);
    *reinterpret_cast<ushort4*>(&xs[0][pidx]) = make_ushort4(f2bf(v.x), f2bf(v.y), f2bf(v.z), f2bf(v.w));
  }
  __syncthreads();

  float cst[4] = {0.f, 0.f, 0.f, 0.f};
  float hreg[4] = {0.f, 0.f, 0.f, 0.f};

  for (int t = 0; t < tmax; ++t) {
    const int cur = t & 1, nxt = cur ^ 1;
    // prefetch x_{t+1} into registers (latency hidden under MFMA)
    float4 pv; bool pact = false;
    if (t + 1 < tmax && t + 1 < plen) {
      int idx = a.nbr[(size_t)pid * K + t + 1];
      pv = *reinterpret_cast<const float4*>(a.hsrc + (size_t)idx * HD + pq * 4);
      pact = true;
    }

    f32x4 C[4];
    #pragma unroll
    for (int g = 0; g < 4; g++) { f32x4 c0 = {bias[g], bias[g], bias[g], bias[g]}; C[g] = c0; }

    #pragma unroll
    for (int s = 0; s < 8; s++) {
      const uint16_t* areg = (s < 4) ? &xs[cur][0] : &hs[cur][0];
      const int koff = (s & 3) * 32 + ((lane >> 4) << 3);
      bfrag af = *reinterpret_cast<const bfrag*>(&areg[(row * 128 + koff) ^ ((row & 7) << 3)]);
      #pragma unroll
      for (int g = 0; g < 4; g++)
        C[g] = __builtin_amdgcn_mfma_f32_16x16x32_bf16(af, Bg[g][s], C[g], 0, 0, 0);
    }

    #pragma unroll
    for (int r = 0; r < 4; r++) {
      if (t < lr[r]) {
        const float iv = sigm(C[0][r]);
        const float fv = sigm(C[1][r]);
        const float gv = tanhft(C[2][r]);
        const float o  = sigm(C[3][r]);
        const float cn = fmaf(fv, cst[r], iv * gv);
        cst[r]  = cn;
        hreg[r] = o * tanhft(cn);
      }
    }
    // writes go to the [nxt] buffers; nobody reads them until after the barrier
    if (pact)
      *reinterpret_cast<ushort4*>(&xs[nxt][pidx]) =
          make_ushort4(f2bf(pv.x), f2bf(pv.y), f2bf(pv.z), f2bf(pv.w));
    #pragma unroll
    for (int r = 0; r < 4; r++)
      hs[nxt][((nb + r) * 128 + myd) ^ (((nb + r) & 7) << 3)] = f2bf(hreg[r]);
    __syncthreads();
  }

  const int fin = tmax & 1;   // buffer holding final h

  // ---- epilogue: out = hdst@Wself^T + hn@Wneigh^T + b (+LN for items) ----
  bfrag Be[8];
  #pragma unroll
  for (int s = 0; s < 8; s++)
    Be[s] = *reinterpret_cast<const bfrag*>(a.We + (size_t)(((wv * 8 + s) * 64 + lane) * 8));

  { // gather hdst into xs[fin]
    float4 v = *reinterpret_cast<const float4*>(a.hdst + (size_t)pid * HD + pq * 4);
    *reinterpret_cast<ushort4*>(&xs[fin][pidx]) = make_ushort4(f2bf(v.x), f2bf(v.y), f2bf(v.z), f2bf(v.w));
  }
  __syncthreads();

  f32x4 O;
  { float bv = a.bvec[myd]; f32x4 o0 = {bv, bv, bv, bv}; O = o0; }
  #pragma unroll
  for (int s = 0; s < 8; s++) {
    const uint16_t* areg = (s < 4) ? &xs[fin][0] : &hs[fin][0];
    const int koff = (s & 3) * 32 + ((lane >> 4) << 3);
    bfrag af = *reinterpret_cast<const bfrag*>(&areg[(row * 128 + koff) ^ ((row & 7) << 3)]);
    O = __builtin_amdgcn_mfma_f32_16x16x32_bf16(af, Be[s], O, 0, 0, 0);
  }

  if (!a.ln) {
    #pragma unroll
    for (int r = 0; r < 4; r++)
      a.out[(size_t)ids_s[nb + r] * HD + myd] = O[r];
  } else {
    #pragma unroll
    for (int r = 0; r < 4; r++) os[nb + r][myd] = O[r];
    __syncthreads();
    const int node = tid >> 5, l = tid & 31;
    float s1 = 0.f, s2 = 0.f, vl[4];
    #pragma unroll
    for (int q = 0; q < 4; q++) {
      float v = os[node][l + q * 32];
      vl[q] = v; s1 += v; s2 += v * v;
    }
    #pragma unroll
    for (int off = 16; off >= 1; off >>= 1) {
      s1 += __shfl_xor(s1, off);
      s2 += __shfl_xor(s2, off);
    }
    const float mu   = s1 * (1.f / 128.f);
    const float var  = s2 * (1.f / 128.f) - mu * mu;
    const float istd = rsqrtf(var + 1e-5f);
    const int oid = ids_s[node];
    #pragma unroll
    for (int q = 0; q < 4; q++) {
      int dd = l + q * 32;
      a.out[(size_t)oid * HD + dd] = (vl[q] - mu) * istd * a.gamma[dd] + a.beta[dd];
    }
  }
}

__global__ __launch_bounds__(128)
void final_k(const float* __restrict__ hi, const int* __restrict__ inv,
             const float* __restrict__ Wf, float* __restrict__ out) {
  __shared__ __align__(16) float rowbuf[HD];
  const int i  = blockIdx.x;
  const int dd = threadIdx.x;
  const int r  = inv[i];
  rowbuf[dd] = hi[(size_t)r * HD + dd];
  __syncthreads();
  float acc = 0.f;
  const float4* w  = reinterpret_cast<const float4*>(Wf + (size_t)dd * HD);
  const float4* rr = reinterpret_cast<const float4*>(rowbuf);
  #pragma unroll 8
  for (int k4 = 0; k4 < 32; k4++) {
    float4 a = w[k4], b = rr[k4];
    acc = fmaf(a.x, b.x, acc); acc = fmaf(a.y, b.y, acc);
    acc = fmaf(a.z, b.z, acc); acc = fmaf(a.w, b.w, acc);
  }
  out[(size_t)i * HD + dd] = (acc > 0.f) ? acc : 0.01f * acc;
}

} // namespace

extern "C" void kernel_launch(void* const* d_in, const int* in_sizes, int n_in,
                              void* d_out, int out_size, void* d_ws, size_t ws_size,
                              hipStream_t stream) {
  (void)in_sizes; (void)n_in; (void)out_size; (void)ws_size;

  const int*   items      = (const int*)d_in[0];
  const int*   nbr_item   = (const int*)d_in[1];
  const int*   len_tag    = (const int*)d_in[2];
  const int*   nbr_tag    = (const int*)d_in[3];
  const int*   len_item   = (const int*)d_in[4];
  const float* item_table = (const float*)d_in[5];
  const float* tag_table  = (const float*)d_in[6];
  const float* Wih_as   = (const float*)d_in[7];
  const float* Whh_as   = (const float*)d_in[8];
  const float* bih_as   = (const float*)d_in[9];
  const float* bhh_as   = (const float*)d_in[10];
  const float* Wself_as  = (const float*)d_in[11];
  const float* Wneigh_as = (const float*)d_in[12];
  const float* b_as      = (const float*)d_in[13];
  const float* Wih_ras   = (const float*)d_in[14];
  const float* Whh_ras   = (const float*)d_in[15];
  const float* bih_ras   = (const float*)d_in[16];
  const float* bhh_ras   = (const float*)d_in[17];
  const float* Wself_ras  = (const float*)d_in[18];
  const float* Wneigh_ras = (const float*)d_in[19];
  const float* b_ras      = (const float*)d_in[20];
  const float* ln_gamma = (const float*)d_in[21];
  const float* ln_beta  = (const float*)d_in[22];
  const float* W_final  = (const float*)d_in[23];
  float* out = (float*)d_out;

  char* p = (char*)d_ws;
  auto take = [&](size_t bytes) -> char* {
    char* r = p;
    p += (bytes + 255) & ~(size_t)255;
    return r;
  };
  int* present = (int*)take((size_t)VOCAB * sizeof(int));
  int* rank    = (int*)take((size_t)(VOCAB + 1) * sizeof(int));
  int* invp    = (int*)take((size_t)N_ITEMS * sizeof(int));
  int* partial = (int*)take(64 * sizeof(int));
  float* hiA = (float*)take((size_t)N_ITEMS * HD * sizeof(float));
  float* hiB = (float*)take((size_t)N_ITEMS * HD * sizeof(float));
  float* htA = (float*)take((size_t)N_TAGS * HD * sizeof(float));
  float* htB = (float*)take((size_t)N_TAGS * HD * sizeof(float));
  uint16_t* WgA = (uint16_t*)take((size_t)GWSZ * 2);
  uint16_t* WgR = (uint16_t*)take((size_t)GWSZ * 2);
  uint16_t* WeA = (uint16_t*)take((size_t)EWSZ * 2);
  uint16_t* WeR = (uint16_t*)take((size_t)EWSZ * 2);
  int* hists = (int*)take((size_t)(KTAG + 1 + KITEM + 1) * sizeof(int));
  int* hist_tag  = hists;
  int* hist_item = hists + KTAG + 1;
  int* base_tag  = (int*)take((size_t)(KTAG + 1) * sizeof(int));
  int* base_item = (int*)take((size_t)(KITEM + 1) * sizeof(int));
  int* ord_tag   = (int*)take((size_t)N_TAGS * sizeof(int));
  int* ord_item  = (int*)take((size_t)N_ITEMS * sizeof(int));

  const int NHIST = KTAG + 1 + KITEM + 1;
  const int NSCAN = (VOCAB + 1023) / 1024;   // 49

  zero_k<<<(VOCAB + NHIST + 255) / 256, 256, 0, stream>>>(present, hists, NHIST);
  mark_k<<<(N_ITEMS + 255) / 256, 256, 0, stream>>>(items, present);
  scanA_k<<<NSCAN, 256, 0, stream>>>(present, partial);
  scanB_k<<<1, 64, 0, stream>>>(partial, rank, NSCAN);
  scanC_k<<<NSCAN, 256, 0, stream>>>(present, partial, rank);
  bpi_k<<<(VOCAB * 32 + N_ITEMS * 32 + N_ITEMS + 255) / 256, 256, 0, stream>>>(
      present, rank, items, item_table, hiA, invp);
  convW_all_k<<<(2 * GWSZ + 2 * EWSZ + 255) / 256, 256, 0, stream>>>(
      Wih_as, Whh_as, Wih_ras, Whh_ras, Wself_as, Wneigh_as, Wself_ras, Wneigh_ras,
      WgA, WgR, WeA, WeR);
  hist_all_k<<<(N_TAGS + N_ITEMS + 255) / 256, 256, 0, stream>>>(len_tag, len_item,
                                                                 hist_tag, hist_item);
  base_k<<<1, 64, 0, stream>>>(hist_tag, base_tag, hist_item, base_item);
  scatter_all_k<<<(N_TAGS + N_ITEMS + 255) / 256, 256, 0, stream>>>(
      len_tag, len_item, base_tag, base_item, ord_tag, ord_item);

  const float* hi_cur = hiA; float* hi_nxt = hiB;
  const float* ht_cur = tag_table; float* ht_nxt = htA;

  for (int l = 0; l < NLAYER; ++l) {
    ConvArgs2 ta, ia;
    ta.hsrc = hi_cur; ta.hdst = ht_cur;
    ta.nbr = nbr_item; ta.len = len_tag; ta.ord = ord_tag;
    ta.Wg = WgA + (size_t)l * 131072; ta.We = WeA + (size_t)l * 32768;
    ta.bih = bih_as + (size_t)l * 512; ta.bhh = bhh_as + (size_t)l * 512;
    ta.bvec = b_as + (size_t)l * HD;
    ta.gamma = nullptr; ta.beta = nullptr;
    ta.out = ht_nxt; ta.K = KTAG; ta.ln = 0; ta.nblk = N_TAGS / 16;

    ia.hsrc = ht_cur; ia.hdst = hi_cur;
    ia.nbr = nbr_tag; ia.len = len_item; ia.ord = ord_item;
    ia.Wg = WgR + (size_t)l * 131072; ia.We = WeR + (size_t)l * 32768;
    ia.bih = bih_ras + (size_t)l * 512; ia.bhh = bhh_ras + (size_t)l * 512;
    ia.bvec = b_ras + (size_t)l * HD;
    ia.gamma = ln_gamma + (size_t)l * HD; ia.beta = ln_beta + (size_t)l * HD;
    ia.out = hi_nxt; ia.K = KITEM; ia.ln = 1; ia.nblk = N_ITEMS / 16;

    layer2_k<<<ta.nblk + ia.nblk, 512, 0, stream>>>(ta, ia);

    hi_cur = hi_nxt; hi_nxt = (hi_cur == hiA) ? hiB : hiA;
    ht_cur = ht_nxt; ht_nxt = (ht_cur == htA) ? htB : htA;
  }

  final_k<<<N_ITEMS, 128, 0, stream>>>(hi_cur, invp, W_final, out);
}

// Round 6
// 307.485 us; speedup vs baseline: 49.8297x; 1.5839x over previous
//
#include <hip/hip_runtime.h>
#include <cstdint>
#include <cstddef>

namespace {

constexpr int N_ITEMS = 10000;
constexpr int N_TAGS  = 2000;
constexpr int VOCAB   = 50000;
constexpr int KTAG    = 32;
constexpr int KITEM   = 8;
constexpr int HD      = 128;
constexpr int NLAYER  = 4;
constexpr int GWSZ = NLAYER * 131072;   // gate frag elems per etype (u16)
constexpr int EWSZ = NLAYER * 32768;    // epilogue frag elems per etype
constexpr int FWSZ = 16384;             // W_final frag elems

constexpr float L2E  = 1.4426950408889634f;
constexpr float TL2E = 2.8853900817779268f;

using bfrag = __attribute__((ext_vector_type(8))) short;
using f32x4 = __attribute__((ext_vector_type(4))) float;

__device__ __forceinline__ float exp2ft(float x) { return __builtin_amdgcn_exp2f(x); }

__device__ __forceinline__ uint16_t f2bf(float f) {
  uint32_t u = __float_as_uint(f);
  u += 0x7fffu + ((u >> 16) & 1u);   // RNE
  return (uint16_t)(u >> 16);
}

__device__ __forceinline__ uint32_t cvt_pk_bf16(float a, float b) {
  uint32_t d;
  asm("v_cvt_pk_bf16_f32 %0, %1, %2" : "=v"(d) : "v"(a), "v"(b));
  return d;
}

__global__ void zero_k(int* present, int* hists, int nh) {
  int i = blockIdx.x * blockDim.x + threadIdx.x;
  if (i < VOCAB) present[i] = 0;
  else if (i - VOCAB < nh) hists[i - VOCAB] = 0;
}

__global__ void mark_k(const int* __restrict__ items, int* __restrict__ present) {
  int i = blockIdx.x * blockDim.x + threadIdx.x;
  if (i < N_ITEMS) present[items[i]] = 1;
}

// ---- 3-phase multi-block scan ----
__global__ __launch_bounds__(256) void scanA_k(const int* __restrict__ present,
                                               int* __restrict__ partial) {
  __shared__ int ws[4];
  const int b = blockIdx.x, tid = threadIdx.x;
  const int base = b * 1024 + tid * 4;
  int s = 0;
  if (base < VOCAB) {
    int4 v = *reinterpret_cast<const int4*>(present + base);
    s = v.x + v.y + v.z + v.w;
  }
  const int lane = tid & 63, wv = tid >> 6;
  #pragma unroll
  for (int off = 32; off >= 1; off >>= 1) s += __shfl_down(s, off);
  if (lane == 0) ws[wv] = s;
  __syncthreads();
  if (tid == 0) partial[b] = ws[0] + ws[1] + ws[2] + ws[3];
}

__global__ void scanB_k(int* __restrict__ partial, int* __restrict__ rank, int nb) {
  const int lane = threadIdx.x;   // 64 threads
  int v = (lane < nb) ? partial[lane] : 0;
  int sc = v;
  #pragma unroll
  for (int off = 1; off < 64; off <<= 1) {
    int u = __shfl_up(sc, off);
    if (lane >= off) sc += u;
  }
  if (lane < nb) partial[lane] = sc - v;
  if (lane == nb - 1) rank[VOCAB] = sc;
}

__global__ __launch_bounds__(256) void scanC_k(const int* __restrict__ present,
                                               const int* __restrict__ partial,
                                               int* __restrict__ rank) {
  __shared__ int ws[4];
  const int b = blockIdx.x, tid = threadIdx.x;
  const int base = b * 1024 + tid * 4;
  int4 v = {0, 0, 0, 0};
  if (base < VOCAB) v = *reinterpret_cast<const int4*>(present + base);
  const int s = v.x + v.y + v.z + v.w;
  const int lane = tid & 63, wv = tid >> 6;
  int sc = s;
  #pragma unroll
  for (int off = 1; off < 64; off <<= 1) {
    int u = __shfl_up(sc, off);
    if (lane >= off) sc += u;
  }
  if (lane == 63) ws[wv] = sc;
  __syncthreads();
  int woff = partial[b];
  for (int w = 0; w < wv; w++) woff += ws[w];
  const int excl = woff + sc - s;
  if (base < VOCAB) {
    int4 r;
    r.x = excl; r.y = excl + v.x; r.z = excl + v.x + v.y; r.w = excl + v.x + v.y + v.z;
    *reinterpret_cast<int4*>(rank + base) = r;
  }
}

// build (compact, to bf16) + pad + inv + tag_table->bf16, fused
__global__ void bpi_k(const int* __restrict__ present, const int* __restrict__ rank,
                      const int* __restrict__ items, const float* __restrict__ table,
                      const float* __restrict__ tagt,
                      uint16_t* __restrict__ hib, uint16_t* __restrict__ ttb,
                      int* __restrict__ inv) {
  int gid = blockIdx.x * blockDim.x + threadIdx.x;
  if (gid < VOCAB * 32) {
    int v = gid >> 5, q = gid & 31;
    if (present[v]) {
      int slot = rank[v];
      float4 x = reinterpret_cast<const float4*>(table + (size_t)v * HD)[q];
      ushort4 u = make_ushort4(f2bf(x.x), f2bf(x.y), f2bf(x.z), f2bf(x.w));
      *reinterpret_cast<ushort4*>(hib + (size_t)slot * HD + q * 4) = u;
    }
  } else if (gid < VOCAB * 32 + N_ITEMS * 32) {
    int g = gid - VOCAB * 32;
    int slot = g >> 5, q = g & 31;
    if (slot >= rank[VOCAB]) {
      float4 x = reinterpret_cast<const float4*>(table)[q];
      ushort4 u = make_ushort4(f2bf(x.x), f2bf(x.y), f2bf(x.z), f2bf(x.w));
      *reinterpret_cast<ushort4*>(hib + (size_t)slot * HD + q * 4) = u;
    }
  } else if (gid < VOCAB * 32 + N_ITEMS * 32 + N_TAGS * 32) {
    int g = gid - VOCAB * 32 - N_ITEMS * 32;
    int tg = g >> 5, q = g & 31;
    float4 x = reinterpret_cast<const float4*>(tagt + (size_t)tg * HD)[q];
    ushort4 u = make_ushort4(f2bf(x.x), f2bf(x.y), f2bf(x.z), f2bf(x.w));
    *reinterpret_cast<ushort4*>(ttb + (size_t)tg * HD + q * 4) = u;
  } else {
    int i = gid - VOCAB * 32 - N_ITEMS * 32 - N_TAGS * 32;
    if (i < N_ITEMS) inv[i] = rank[items[i]];
  }
}

// All weight->fragment transforms fused. Frag lane map (A and B identical):
// 16-index = lane&15, k = s*32 + (lane>>4)*8 + j.
// Gate: [layer][w:3][g:2][s:3][lane:6][j:3]; value W[g*128+w*16+(lane&15)][k],
//       k<128 -> Wih else Whh; PRE-SCALED by -log2e (g!=2) / +2log2e (g==2).
// Ep:   [layer][w:3][s:3][lane:6][j:3]; Wself/Wneigh (no scale).
// Wf:   [w:3][s:2][lane:6][j:3] (K=128).
__global__ void convW_all_k(const float* __restrict__ WihA, const float* __restrict__ WhhA,
                            const float* __restrict__ WihR, const float* __restrict__ WhhR,
                            const float* __restrict__ WsA,  const float* __restrict__ WnA,
                            const float* __restrict__ WsR,  const float* __restrict__ WnR,
                            const float* __restrict__ Wf,
                            uint16_t* __restrict__ GgA, uint16_t* __restrict__ GgR,
                            uint16_t* __restrict__ GeA, uint16_t* __restrict__ GeR,
                            uint16_t* __restrict__ GWf) {
  int o = blockIdx.x * blockDim.x + threadIdx.x;
  if (o < 2 * GWSZ) {
    const bool A = (o < GWSZ);
    int oo = A ? o : o - GWSZ;
    const float* Wih = A ? WihA : WihR;
    const float* Whh = A ? WhhA : WhhR;
    uint16_t* outp = A ? GgA : GgR;
    int j = oo & 7, lane = (oo >> 3) & 63, s = (oo >> 9) & 7, g = (oo >> 12) & 3,
        w = (oo >> 14) & 7, l = oo >> 17;
    int k = s * 32 + ((lane >> 4) << 3) + j;
    int c = g * 128 + w * 16 + (lane & 15);
    float v = (k < 128) ? Wih[((size_t)l * 512 + c) * 128 + k]
                        : Whh[((size_t)l * 512 + c) * 128 + (k - 128)];
    v *= (g == 2) ? TL2E : -L2E;
    outp[oo] = f2bf(v);
  } else if (o < 2 * GWSZ + 2 * EWSZ) {
    int oe = o - 2 * GWSZ;
    const bool A = (oe < EWSZ);
    int oo = A ? oe : oe - EWSZ;
    const float* Ws = A ? WsA : WsR;
    const float* Wn = A ? WnA : WnR;
    uint16_t* outp = A ? GeA : GeR;
    int j = oo & 7, lane = (oo >> 3) & 63, s = (oo >> 9) & 7, w = (oo >> 12) & 7, l = oo >> 15;
    int k = s * 32 + ((lane >> 4) << 3) + j;
    int c = w * 16 + (lane & 15);
    float v = (k < 128) ? Ws[((size_t)l * 128 + c) * 128 + k]
                        : Wn[((size_t)l * 128 + c) * 128 + (k - 128)];
    outp[oo] = f2bf(v);
  } else if (o < 2 * GWSZ + 2 * EWSZ + FWSZ) {
    int oo = o - 2 * GWSZ - 2 * EWSZ;
    int j = oo & 7, lane = (oo >> 3) & 63, s = (oo >> 9) & 3, w = oo >> 11;
    int k = s * 32 + ((lane >> 4) << 3) + j;
    int c = w * 16 + (lane & 15);
    GWf[oo] = f2bf(Wf[(size_t)c * 128 + k]);
  }
}

// ---- length bucketing (counting sort, descending) ----
__global__ void hist_all_k(const int* __restrict__ len_tag, const int* __restrict__ len_item,
                           int* __restrict__ hist_tag, int* __restrict__ hist_item) {
  int i = blockIdx.x * blockDim.x + threadIdx.x;
  if (i < N_TAGS) atomicAdd(&hist_tag[len_tag[i]], 1);
  int j = i - N_TAGS;
  if (j >= 0 && j < N_ITEMS) atomicAdd(&hist_item[len_item[j]], 1);
}

__global__ void base_k(const int* __restrict__ hist_tag, int* __restrict__ base_tag,
                       const int* __restrict__ hist_item, int* __restrict__ base_item) {
  if (threadIdx.x == 0) {
    int acc = 0;
    for (int l = KTAG; l >= 1; --l) { base_tag[l] = acc; acc += hist_tag[l]; }
    acc = 0;
    for (int l = KITEM; l >= 1; --l) { base_item[l] = acc; acc += hist_item[l]; }
  }
}

__global__ void scatter_all_k(const int* __restrict__ len_tag, const int* __restrict__ len_item,
                              int* __restrict__ base_tag, int* __restrict__ base_item,
                              int* __restrict__ ord_tag, int* __restrict__ ord_item) {
  int i = blockIdx.x * blockDim.x + threadIdx.x;
  if (i < N_TAGS) {
    int pos = atomicAdd(&base_tag[len_tag[i]], 1);
    ord_tag[pos] = i;
  }
  int j = i - N_TAGS;
  if (j >= 0 && j < N_ITEMS) {
    int pos = atomicAdd(&base_item[len_item[j]], 1);
    ord_item[pos] = j;
  }
}

struct ConvArgs3 {
  const uint16_t* hsrc; const uint16_t* hdst;   // bf16 features
  const int* nbr; const int* len; const int* ord;
  const uint16_t* Wg;   // gate A-frags (pre-scaled), layer slice
  const uint16_t* We;   // epilogue A-frags, layer slice
  const float* bih; const float* bhh; const float* bvec;
  const float* gamma; const float* beta;
  uint16_t* outbf;      // bf16 output features
  int K; int ln; int nblk;
};

// Block = 16 dst nodes, 8 waves. A = weights (VGPR/AGPR-resident), B = acts (LDS).
// D[dim][node]: lane owns node n=lane&15, dims d0..d0+3 (d0 = wv*16+(lane>>4)*4).
// One barrier per step; x-prefetch depth 2; packed bf16 h-writes.
__global__ __launch_bounds__(512, 2)
void layer3_k(ConvArgs3 targ, ConvArgs3 iarg) {
  const bool is_tag = ((int)blockIdx.x < targ.nblk);
  const ConvArgs3& a = is_tag ? targ : iarg;
  const int blk  = is_tag ? (int)blockIdx.x : ((int)blockIdx.x - targ.nblk);
  const int tid  = threadIdx.x;
  const int wv   = tid >> 6;
  const int lane = tid & 63;
  const int n0   = blk * 16;
  const int K    = a.K;

  __shared__ __align__(16) uint16_t xs[2][2048];
  __shared__ __align__(16) uint16_t hs[2][2048];
  __shared__ float2 red[8][16];
  __shared__ int ids_s[16], lens_s[16];

  if (tid < 16) {
    int id = a.ord[n0 + tid];
    ids_s[tid]  = id;
    lens_s[tid] = a.len[id];
  }
  *reinterpret_cast<ushort4*>(&hs[0][tid * 4]) = make_ushort4(0, 0, 0, 0);
  __syncthreads();

  const int n  = lane & 15;                 // node column
  const int dq = lane >> 4;                 // dim quarter
  const int d0 = wv * 16 + dq * 4;          // first of lane's 4 dims
  const int lenN = lens_s[n];
  const int pnode = tid >> 5, pq = tid & 31;
  const int pid  = ids_s[pnode];
  const int plen = lens_s[pnode];
  const int pidx = (pnode * 128 + pq * 4) ^ ((pnode & 7) << 3);   // u16 units

  int tmax = 1;
  #pragma unroll
  for (int b = 0; b < 16; b++) tmax = max(tmax, lens_s[b]);

  int offs[4];
  #pragma unroll
  for (int s = 0; s < 4; s++)
    offs[s] = (n * 128 + s * 32 + dq * 8) ^ ((n & 7) << 3);
  const int hwo = (n * 128 + d0) ^ ((n & 7) << 3);

  // resident A-frags (gate weights, pre-scaled)
  bfrag Ag[4][8];
  #pragma unroll
  for (int g = 0; g < 4; g++) {
    #pragma unroll
    for (int s = 0; s < 8; s++)
      Ag[g][s] = *reinterpret_cast<const bfrag*>(
          a.Wg + (size_t)((((wv * 4 + g) * 8 + s) * 64 + lane) * 8));
  }

  f32x4 bias4[4];
  #pragma unroll
  for (int g = 0; g < 4; g++) {
    f32x4 bi = *reinterpret_cast<const f32x4*>(a.bih + g * 128 + d0);
    f32x4 bh = *reinterpret_cast<const f32x4*>(a.bhh + g * 128 + d0);
    const float sc = (g == 2) ? TL2E : -L2E;
    bias4[g] = (bi + bh) * sc;
  }

  const int* nbrp = a.nbr + (size_t)pid * K;
  { // stage x_0 (len >= 1 always)
    const uint16_t* src = a.hsrc + (size_t)nbrp[0] * HD + pq * 4;
    *reinterpret_cast<ushort4*>(&xs[0][pidx]) = *reinterpret_cast<const ushort4*>(src);
  }
  ushort4 xq = make_ushort4(0, 0, 0, 0);
  if (plen > 1)
    xq = *reinterpret_cast<const ushort4*>(a.hsrc + (size_t)nbrp[1] * HD + pq * 4);
  int idxn = (plen > 2) ? nbrp[2] : 0;
  __syncthreads();

  float cst[4] = {0.f, 0.f, 0.f, 0.f};
  uint2 hpk = {0u, 0u};

  for (int t = 0; t < tmax; ++t) {
    const int cur = t & 1, nxt = cur ^ 1;

    f32x4 C[4];
    #pragma unroll
    for (int g = 0; g < 4; g++) C[g] = bias4[g];

    #pragma unroll
    for (int s = 0; s < 4; s++) {
      bfrag bx = *reinterpret_cast<const bfrag*>(&xs[cur][offs[s]]);
      #pragma unroll
      for (int g = 0; g < 4; g++)
        C[g] = __builtin_amdgcn_mfma_f32_16x16x32_bf16(Ag[g][s], bx, C[g], 0, 0, 0);
    }
    #pragma unroll
    for (int s = 0; s < 4; s++) {
      bfrag bh = *reinterpret_cast<const bfrag*>(&hs[cur][offs[s]]);
      #pragma unroll
      for (int g = 0; g < 4; g++)
        C[g] = __builtin_amdgcn_mfma_f32_16x16x32_bf16(Ag[g][s + 4], bh, C[g], 0, 0, 0);
    }

    if (t < lenN) {
      float hv[4];
      #pragma unroll
      for (int r = 0; r < 4; r++) {
        const float iv = __builtin_amdgcn_rcpf(1.0f + exp2ft(C[0][r]));
        const float fv = __builtin_amdgcn_rcpf(1.0f + exp2ft(C[1][r]));
        const float gv = 1.0f - 2.0f * __builtin_amdgcn_rcpf(1.0f + exp2ft(C[2][r]));
        const float ov = __builtin_amdgcn_rcpf(1.0f + exp2ft(C[3][r]));
        const float cn = fmaf(fv, cst[r], iv * gv);
        cst[r] = cn;
        const float th = 1.0f - 2.0f * __builtin_amdgcn_rcpf(1.0f + exp2ft(cn * TL2E));
        hv[r] = ov * th;
      }
      hpk.x = cvt_pk_bf16(hv[0], hv[1]);
      hpk.y = cvt_pk_bf16(hv[2], hv[3]);
    }

    if (t + 1 < tmax) {
      if (t + 1 < plen)
        *reinterpret_cast<ushort4*>(&xs[nxt][pidx]) = xq;
      if (t + 2 < plen)
        xq = *reinterpret_cast<const ushort4*>(a.hsrc + (size_t)idxn * HD + pq * 4);
      idxn = (t + 3 < plen) ? nbrp[t + 3] : 0;
    }
    *reinterpret_cast<uint2*>(&hs[nxt][hwo]) = hpk;
    __syncthreads();
  }

  const int fin = tmax & 1;

  // ---- epilogue: out = hdst@Wself^T + hn@Wneigh^T + b (+LN for items) ----
  bfrag Ae[8];
  #pragma unroll
  for (int s = 0; s < 8; s++)
    Ae[s] = *reinterpret_cast<const bfrag*>(
        a.We + (size_t)(((wv * 8 + s) * 64 + lane) * 8));

  { // stage hdst rows (already bf16)
    const uint16_t* src = a.hdst + (size_t)pid * HD + pq * 4;
    *reinterpret_cast<ushort4*>(&xs[fin][pidx]) = *reinterpret_cast<const ushort4*>(src);
  }
  __syncthreads();

  f32x4 O = *reinterpret_cast<const f32x4*>(a.bvec + d0);
  #pragma unroll
  for (int s = 0; s < 4; s++) {
    bfrag bx = *reinterpret_cast<const bfrag*>(&xs[fin][offs[s]]);
    O = __builtin_amdgcn_mfma_f32_16x16x32_bf16(Ae[s], bx, O, 0, 0, 0);
  }
  #pragma unroll
  for (int s = 0; s < 4; s++) {
    bfrag bh = *reinterpret_cast<const bfrag*>(&hs[fin][offs[s]]);
    O = __builtin_amdgcn_mfma_f32_16x16x32_bf16(Ae[s + 4], bh, O, 0, 0, 0);
  }

  const int oid = ids_s[n];
  if (!a.ln) {
    uint2 pk;
    pk.x = cvt_pk_bf16(O[0], O[1]);
    pk.y = cvt_pk_bf16(O[2], O[3]);
    *reinterpret_cast<uint2*>(a.outbf + (size_t)oid * HD + d0) = pk;
  } else {
    float s1 = O[0] + O[1] + O[2] + O[3];
    float s2 = O[0] * O[0] + O[1] * O[1] + O[2] * O[2] + O[3] * O[3];
    s1 += __shfl_xor(s1, 16); s2 += __shfl_xor(s2, 16);
    s1 += __shfl_xor(s1, 32); s2 += __shfl_xor(s2, 32);
    if (dq == 0) red[wv][n] = make_float2(s1, s2);
    __syncthreads();
    float m1 = 0.f, m2 = 0.f;
    #pragma unroll
    for (int w = 0; w < 8; w++) {
      float2 v = red[w][n];
      m1 += v.x; m2 += v.y;
    }
    const float mu   = m1 * (1.f / 128.f);
    const float var  = m2 * (1.f / 128.f) - mu * mu;
    const float istd = rsqrtf(var + 1e-5f);
    f32x4 gm = *reinterpret_cast<const f32x4*>(a.gamma + d0);
    f32x4 bt = *reinterpret_cast<const f32x4*>(a.beta + d0);
    float v[4];
    #pragma unroll
    for (int r = 0; r < 4; r++)
      v[r] = (O[r] - mu) * istd * gm[r] + bt[r];
    uint2 pk;
    pk.x = cvt_pk_bf16(v[0], v[1]);
    pk.y = cvt_pk_bf16(v[2], v[3]);
    *reinterpret_cast<uint2*>(a.outbf + (size_t)oid * HD + d0) = pk;
  }
}

// final Linear (no bias) + LeakyReLU, gathered by inv. Block = 16 outputs.
__global__ __launch_bounds__(512)
void final2_k(const uint16_t* __restrict__ hib, const int* __restrict__ inv,
              const uint16_t* __restrict__ fWf, float* __restrict__ out) {
  __shared__ __align__(16) uint16_t rs[2048];
  __shared__ int rid[16];
  const int tid = threadIdx.x, wv = tid >> 6, lane = tid & 63;
  const int i0 = blockIdx.x * 16;
  if (tid < 16) rid[tid] = inv[i0 + tid];
  __syncthreads();
  const int pnode = tid >> 5, pq = tid & 31;
  const int pidx = (pnode * 128 + pq * 4) ^ ((pnode & 7) << 3);
  *reinterpret_cast<ushort4*>(&rs[pidx]) =
      *reinterpret_cast<const ushort4*>(hib + (size_t)rid[pnode] * HD + pq * 4);
  __syncthreads();

  const int n = lane & 15, dq = lane >> 4;
  const int d0 = wv * 16 + dq * 4;
  bfrag Af[4];
  #pragma unroll
  for (int s = 0; s < 4; s++)
    Af[s] = *reinterpret_cast<const bfrag*>(fWf + (size_t)(((wv * 4 + s) * 64 + lane) * 8));

  f32x4 O = {0.f, 0.f, 0.f, 0.f};
  #pragma unroll
  for (int s = 0; s < 4; s++) {
    const int off = (n * 128 + s * 32 + dq * 8) ^ ((n & 7) << 3);
    bfrag b = *reinterpret_cast<const bfrag*>(&rs[off]);
    O = __builtin_amdgcn_mfma_f32_16x16x32_bf16(Af[s], b, O, 0, 0, 0);
  }
  float4 res;
  res.x = (O[0] > 0.f) ? O[0] : 0.01f * O[0];
  res.y = (O[1] > 0.f) ? O[1] : 0.01f * O[1];
  res.z = (O[2] > 0.f) ? O[2] : 0.01f * O[2];
  res.w = (O[3] > 0.f) ? O[3] : 0.01f * O[3];
  *reinterpret_cast<float4*>(out + (size_t)(i0 + n) * HD + d0) = res;
}

} // namespace

extern "C" void kernel_launch(void* const* d_in, const int* in_sizes, int n_in,
                              void* d_out, int out_size, void* d_ws, size_t ws_size,
                              hipStream_t stream) {
  (void)in_sizes; (void)n_in; (void)out_size; (void)ws_size;

  const int*   items      = (const int*)d_in[0];
  const int*   nbr_item   = (const int*)d_in[1];
  const int*   len_tag    = (const int*)d_in[2];
  const int*   nbr_tag    = (const int*)d_in[3];
  const int*   len_item   = (const int*)d_in[4];
  const float* item_table = (const float*)d_in[5];
  const float* tag_table  = (const float*)d_in[6];
  const float* Wih_as   = (const float*)d_in[7];
  const float* Whh_as   = (const float*)d_in[8];
  const float* bih_as   = (const float*)d_in[9];
  const float* bhh_as   = (const float*)d_in[10];
  const float* Wself_as  = (const float*)d_in[11];
  const float* Wneigh_as = (const float*)d_in[12];
  const float* b_as      = (const float*)d_in[13];
  const float* Wih_ras   = (const float*)d_in[14];
  const float* Whh_ras   = (const float*)d_in[15];
  const float* bih_ras   = (const float*)d_in[16];
  const float* bhh_ras   = (const float*)d_in[17];
  const float* Wself_ras  = (const float*)d_in[18];
  const float* Wneigh_ras = (const float*)d_in[19];
  const float* b_ras      = (const float*)d_in[20];
  const float* ln_gamma = (const float*)d_in[21];
  const float* ln_beta  = (const float*)d_in[22];
  const float* W_final  = (const float*)d_in[23];
  float* out = (float*)d_out;

  char* p = (char*)d_ws;
  auto take = [&](size_t bytes) -> char* {
    char* r = p;
    p += (bytes + 255) & ~(size_t)255;
    return r;
  };
  int* present = (int*)take((size_t)VOCAB * sizeof(int));
  int* rank    = (int*)take((size_t)(VOCAB + 1) * sizeof(int));
  int* invp    = (int*)take((size_t)N_ITEMS * sizeof(int));
  int* partial = (int*)take(64 * sizeof(int));
  uint16_t* hti0 = (uint16_t*)take((size_t)N_ITEMS * HD * 2);
  uint16_t* htiA = (uint16_t*)take((size_t)N_ITEMS * HD * 2);
  uint16_t* htiB = (uint16_t*)take((size_t)N_ITEMS * HD * 2);
  uint16_t* htt0 = (uint16_t*)take((size_t)N_TAGS * HD * 2);
  uint16_t* httA = (uint16_t*)take((size_t)N_TAGS * HD * 2);
  uint16_t* httB = (uint16_t*)take((size_t)N_TAGS * HD * 2);
  uint16_t* WgA = (uint16_t*)take((size_t)GWSZ * 2);
  uint16_t* WgR = (uint16_t*)take((size_t)GWSZ * 2);
  uint16_t* WeA = (uint16_t*)take((size_t)EWSZ * 2);
  uint16_t* WeR = (uint16_t*)take((size_t)EWSZ * 2);
  uint16_t* fWf = (uint16_t*)take((size_t)FWSZ * 2);
  int* hists = (int*)take((size_t)(KTAG + 1 + KITEM + 1) * sizeof(int));
  int* hist_tag  = hists;
  int* hist_item = hists + KTAG + 1;
  int* base_tag  = (int*)take((size_t)(KTAG + 1) * sizeof(int));
  int* base_item = (int*)take((size_t)(KITEM + 1) * sizeof(int));
  int* ord_tag   = (int*)take((size_t)N_TAGS * sizeof(int));
  int* ord_item  = (int*)take((size_t)N_ITEMS * sizeof(int));

  const int NHIST = KTAG + 1 + KITEM + 1;
  const int NSCAN = (VOCAB + 1023) / 1024;   // 49
  const int NBPI  = VOCAB * 32 + N_ITEMS * 32 + N_TAGS * 32 + N_ITEMS;
  const int NCONV = 2 * GWSZ + 2 * EWSZ + FWSZ;

  zero_k<<<(VOCAB + NHIST + 255) / 256, 256, 0, stream>>>(present, hists, NHIST);
  mark_k<<<(N_ITEMS + 255) / 256, 256, 0, stream>>>(items, present);
  scanA_k<<<NSCAN, 256, 0, stream>>>(present, partial);
  scanB_k<<<1, 64, 0, stream>>>(partial, rank, NSCAN);
  scanC_k<<<NSCAN, 256, 0, stream>>>(present, partial, rank);
  bpi_k<<<(NBPI + 255) / 256, 256, 0, stream>>>(present, rank, items, item_table,
                                                tag_table, hti0, htt0, invp);
  convW_all_k<<<(NCONV + 255) / 256, 256, 0, stream>>>(
      Wih_as, Whh_as, Wih_ras, Whh_ras, Wself_as, Wneigh_as, Wself_ras, Wneigh_ras,
      W_final, WgA, WgR, WeA, WeR, fWf);
  hist_all_k<<<(N_TAGS + N_ITEMS + 255) / 256, 256, 0, stream>>>(len_tag, len_item,
                                                                 hist_tag, hist_item);
  base_k<<<1, 64, 0, stream>>>(hist_tag, base_tag, hist_item, base_item);
  scatter_all_k<<<(N_TAGS + N_ITEMS + 255) / 256, 256, 0, stream>>>(
      len_tag, len_item, base_tag, base_item, ord_tag, ord_item);

  const uint16_t* hi_cur = hti0; uint16_t* hi_nxt = htiA;
  const uint16_t* ht_cur = htt0; uint16_t* ht_nxt = httA;

  for (int l = 0; l < NLAYER; ++l) {
    ConvArgs3 ta, ia;
    ta.hsrc = hi_cur; ta.hdst = ht_cur;
    ta.nbr = nbr_item; ta.len = len_tag; ta.ord = ord_tag;
    ta.Wg = WgA + (size_t)l * 131072; ta.We = WeA + (size_t)l * 32768;
    ta.bih = bih_as + (size_t)l * 512; ta.bhh = bhh_as + (size_t)l * 512;
    ta.bvec = b_as + (size_t)l * HD;
    ta.gamma = nullptr; ta.beta = nullptr;
    ta.outbf = ht_nxt; ta.K = KTAG; ta.ln = 0; ta.nblk = N_TAGS / 16;

    ia.hsrc = ht_cur; ia.hdst = hi_cur;
    ia.nbr = nbr_tag; ia.len = len_item; ia.ord = ord_item;
    ia.Wg = WgR + (size_t)l * 131072; ia.We = WeR + (size_t)l * 32768;
    ia.bih = bih_ras + (size_t)l * 512; ia.bhh = bhh_ras + (size_t)l * 512;
    ia.bvec = b_ras + (size_t)l * HD;
    ia.gamma = ln_gamma + (size_t)l * HD; ia.beta = ln_beta + (size_t)l * HD;
    ia.outbf = hi_nxt; ia.K = KITEM; ia.ln = 1; ia.nblk = N_ITEMS / 16;

    layer3_k<<<ta.nblk + ia.nblk, 512, 0, stream>>>(ta, ia);

    hi_cur = hi_nxt; hi_nxt = (hi_cur == htiA) ? htiB : htiA;
    ht_cur = ht_nxt; ht_nxt = (ht_cur == httA) ? httB : httA;
  }

  final2_k<<<N_ITEMS / 16, 512, 0, stream>>>(hi_cur, invp, fWf, out);
}

// Round 7
// 303.719 us; speedup vs baseline: 50.4476x; 1.0124x over previous
//
#include <hip/hip_runtime.h>
#include <cstdint>
#include <cstddef>

namespace {

constexpr int N_ITEMS = 10000;
constexpr int N_TAGS  = 2000;
constexpr int VOCAB   = 50000;
constexpr int KTAG    = 32;
constexpr int KITEM   = 8;
constexpr int HD      = 128;
constexpr int NLAYER  = 4;
constexpr int GWSZ = NLAYER * 131072;   // gate frag elems per etype (u16)
constexpr int EWSZ = NLAYER * 32768;    // epilogue frag elems per etype
constexpr int FWSZ = 16384;             // W_final frag elems
constexpr int NSCAN = (VOCAB + 1023) / 1024;   // 49

constexpr float L2E  = 1.4426950408889634f;
constexpr float TL2E = 2.8853900817779268f;

using bfrag = __attribute__((ext_vector_type(8))) short;
using f32x4 = __attribute__((ext_vector_type(4))) float;

__device__ __forceinline__ float exp2ft(float x) { return __builtin_amdgcn_exp2f(x); }

__device__ __forceinline__ uint16_t f2bf(float f) {
  uint32_t u = __float_as_uint(f);
  u += 0x7fffu + ((u >> 16) & 1u);   // RNE
  return (uint16_t)(u >> 16);
}

__device__ __forceinline__ uint32_t cvt_pk_bf16(float a, float b) {
  uint32_t d;
  asm("v_cvt_pk_bf16_f32 %0, %1, %2" : "=v"(d) : "v"(a), "v"(b));
  return d;
}

__global__ void zero_k(int* present, int* hists, int nh) {
  int i = blockIdx.x * blockDim.x + threadIdx.x;
  if (i < VOCAB) present[i] = 0;
  else if (i - VOCAB < nh) hists[i - VOCAB] = 0;
}

// mark presence + length histograms (all independent, post-zero)
__global__ void markhist_k(const int* __restrict__ items, int* __restrict__ present,
                           const int* __restrict__ len_tag, const int* __restrict__ len_item,
                           int* __restrict__ hist_tag, int* __restrict__ hist_item) {
  int i = blockIdx.x * blockDim.x + threadIdx.x;
  if (i < N_ITEMS) present[items[i]] = 1;
  if (i < N_TAGS) atomicAdd(&hist_tag[len_tag[i]], 1);
  int j = i - N_TAGS;
  if (j >= 0 && j < N_ITEMS) atomicAdd(&hist_item[len_item[j]], 1);
}

// per-1024-chunk sums; block 0 thread 0 also computes bucket bases (hist ready)
__global__ __launch_bounds__(256) void scanA_k(const int* __restrict__ present,
                                               int* __restrict__ partial,
                                               const int* __restrict__ hist_tag,
                                               int* __restrict__ base_tag,
                                               const int* __restrict__ hist_item,
                                               int* __restrict__ base_item) {
  __shared__ int ws[4];
  const int b = blockIdx.x, tid = threadIdx.x;
  const int base = b * 1024 + tid * 4;
  int s = 0;
  if (base < VOCAB) {
    int4 v = *reinterpret_cast<const int4*>(present + base);
    s = v.x + v.y + v.z + v.w;
  }
  const int lane = tid & 63, wv = tid >> 6;
  #pragma unroll
  for (int off = 32; off >= 1; off >>= 1) s += __shfl_down(s, off);
  if (lane == 0) ws[wv] = s;
  __syncthreads();
  if (tid == 0) partial[b] = ws[0] + ws[1] + ws[2] + ws[3];
  if (b == 0 && tid == 0) {
    int acc = 0;
    for (int l = KTAG; l >= 1; --l) { base_tag[l] = acc; acc += hist_tag[l]; }
    acc = 0;
    for (int l = KITEM; l >= 1; --l) { base_item[l] = acc; acc += hist_item[l]; }
  }
}

// final scan: each block redundantly wave-scans the 49 partials (kills scanB launch)
__global__ __launch_bounds__(256) void scanC_k(const int* __restrict__ present,
                                               const int* __restrict__ partial,
                                               int* __restrict__ rank) {
  __shared__ int ws[4];
  __shared__ int pscan[64];
  const int b = blockIdx.x, tid = threadIdx.x;
  if (tid < 64) {
    int v = (tid < NSCAN) ? partial[tid] : 0;
    int sc = v;
    #pragma unroll
    for (int off = 1; off < 64; off <<= 1) {
      int u = __shfl_up(sc, off);
      if (tid >= off) sc += u;
    }
    pscan[tid] = sc;   // inclusive
  }
  const int base = b * 1024 + tid * 4;
  int4 v = {0, 0, 0, 0};
  if (base < VOCAB) v = *reinterpret_cast<const int4*>(present + base);
  const int s = v.x + v.y + v.z + v.w;
  const int lane = tid & 63, wv = tid >> 6;
  int sc = s;
  #pragma unroll
  for (int off = 1; off < 64; off <<= 1) {
    int u = __shfl_up(sc, off);
    if (lane >= off) sc += u;
  }
  if (lane == 63) ws[wv] = sc;
  __syncthreads();
  int woff = (b > 0) ? pscan[b - 1] : 0;
  for (int w = 0; w < wv; w++) woff += ws[w];
  const int excl = woff + sc - s;
  if (base < VOCAB) {
    int4 r;
    r.x = excl; r.y = excl + v.x; r.z = excl + v.x + v.y; r.w = excl + v.x + v.y + v.z;
    *reinterpret_cast<int4*>(rank + base) = r;
  }
  if (b == 0 && tid == 0) rank[VOCAB] = pscan[NSCAN - 1];
}

// prep_k = bpi (compact+pad+inv, fp32->bf16) + convW (all frag transforms) + scatter
constexpr int NBPI  = VOCAB * 32 + N_ITEMS * 32 + N_TAGS * 32 + N_ITEMS;
constexpr int NCONV = 2 * GWSZ + 2 * EWSZ + FWSZ;

__global__ void prep_k(const int* __restrict__ present, const int* __restrict__ rank,
                       const int* __restrict__ items, const float* __restrict__ table,
                       const float* __restrict__ tagt,
                       uint16_t* __restrict__ hib, uint16_t* __restrict__ ttb,
                       int* __restrict__ inv,
                       const float* __restrict__ WihA, const float* __restrict__ WhhA,
                       const float* __restrict__ WihR, const float* __restrict__ WhhR,
                       const float* __restrict__ WsA,  const float* __restrict__ WnA,
                       const float* __restrict__ WsR,  const float* __restrict__ WnR,
                       const float* __restrict__ Wf,
                       uint16_t* __restrict__ GgA, uint16_t* __restrict__ GgR,
                       uint16_t* __restrict__ GeA, uint16_t* __restrict__ GeR,
                       uint16_t* __restrict__ GWf,
                       const int* __restrict__ len_tag, const int* __restrict__ len_item,
                       int* __restrict__ base_tag, int* __restrict__ base_item,
                       int* __restrict__ ord_tag, int* __restrict__ ord_item) {
  int gid = blockIdx.x * blockDim.x + threadIdx.x;
  if (gid < VOCAB * 32) {
    int v = gid >> 5, q = gid & 31;
    if (present[v]) {
      int slot = rank[v];
      float4 x = reinterpret_cast<const float4*>(table + (size_t)v * HD)[q];
      ushort4 u = make_ushort4(f2bf(x.x), f2bf(x.y), f2bf(x.z), f2bf(x.w));
      *reinterpret_cast<ushort4*>(hib + (size_t)slot * HD + q * 4) = u;
    }
  } else if (gid < VOCAB * 32 + N_ITEMS * 32) {
    int g = gid - VOCAB * 32;
    int slot = g >> 5, q = g & 31;
    if (slot >= rank[VOCAB]) {
      float4 x = reinterpret_cast<const float4*>(table)[q];
      ushort4 u = make_ushort4(f2bf(x.x), f2bf(x.y), f2bf(x.z), f2bf(x.w));
      *reinterpret_cast<ushort4*>(hib + (size_t)slot * HD + q * 4) = u;
    }
  } else if (gid < VOCAB * 32 + N_ITEMS * 32 + N_TAGS * 32) {
    int g = gid - VOCAB * 32 - N_ITEMS * 32;
    int tg = g >> 5, q = g & 31;
    float4 x = reinterpret_cast<const float4*>(tagt + (size_t)tg * HD)[q];
    ushort4 u = make_ushort4(f2bf(x.x), f2bf(x.y), f2bf(x.z), f2bf(x.w));
    *reinterpret_cast<ushort4*>(ttb + (size_t)tg * HD + q * 4) = u;
  } else if (gid < NBPI) {
    int i = gid - VOCAB * 32 - N_ITEMS * 32 - N_TAGS * 32;
    if (i < N_ITEMS) inv[i] = rank[items[i]];
  } else if (gid < NBPI + 2 * GWSZ) {
    int o = gid - NBPI;
    const bool A = (o < GWSZ);
    int oo = A ? o : o - GWSZ;
    const float* Wih = A ? WihA : WihR;
    const float* Whh = A ? WhhA : WhhR;
    uint16_t* outp = A ? GgA : GgR;
    int j = oo & 7, lane = (oo >> 3) & 63, s = (oo >> 9) & 7, g = (oo >> 12) & 3,
        w = (oo >> 14) & 7, l = oo >> 17;
    int k = s * 32 + ((lane >> 4) << 3) + j;
    int c = g * 128 + w * 16 + (lane & 15);
    float v = (k < 128) ? Wih[((size_t)l * 512 + c) * 128 + k]
                        : Whh[((size_t)l * 512 + c) * 128 + (k - 128)];
    v *= (g == 2) ? TL2E : -L2E;
    outp[oo] = f2bf(v);
  } else if (gid < NBPI + 2 * GWSZ + 2 * EWSZ) {
    int oe = gid - NBPI - 2 * GWSZ;
    const bool A = (oe < EWSZ);
    int oo = A ? oe : oe - EWSZ;
    const float* Ws = A ? WsA : WsR;
    const float* Wn = A ? WnA : WnR;
    uint16_t* outp = A ? GeA : GeR;
    int j = oo & 7, lane = (oo >> 3) & 63, s = (oo >> 9) & 7, w = (oo >> 12) & 7, l = oo >> 15;
    int k = s * 32 + ((lane >> 4) << 3) + j;
    int c = w * 16 + (lane & 15);
    float v = (k < 128) ? Ws[((size_t)l * 128 + c) * 128 + k]
                        : Wn[((size_t)l * 128 + c) * 128 + (k - 128)];
    outp[oo] = f2bf(v);
  } else if (gid < NBPI + NCONV) {
    int oo = gid - NBPI - 2 * GWSZ - 2 * EWSZ;
    int j = oo & 7, lane = (oo >> 3) & 63, s = (oo >> 9) & 3, w = oo >> 11;
    int k = s * 32 + ((lane >> 4) << 3) + j;
    int c = w * 16 + (lane & 15);
    GWf[oo] = f2bf(Wf[(size_t)c * 128 + k]);
  } else {
    int i = gid - NBPI - NCONV;
    if (i < N_TAGS) {
      int pos = atomicAdd(&base_tag[len_tag[i]], 1);
      ord_tag[pos] = i;
    }
    int j = i - N_TAGS;
    if (j >= 0 && j < N_ITEMS) {
      int pos = atomicAdd(&base_item[len_item[j]], 1);
      ord_item[pos] = j;
    }
  }
}

struct ConvArgs3 {
  const uint16_t* hsrc; const uint16_t* hdst;   // bf16 features
  const int* nbr; const int* len; const int* ord;
  const uint16_t* Wg;   // gate A-frags (pre-scaled), layer slice
  const uint16_t* We;   // epilogue A-frags, layer slice
  const float* bih; const float* bhh; const float* bvec;
  const float* gamma; const float* beta;
  uint16_t* outbf;
  int K; int ln; int nblk;
};

// Block = 16 dst nodes, 8 waves. A = weights (reg-resident), B = acts (LDS).
// Software-pipelined: Cx_{t+1} (x-side, independent) computed during step t;
// serial chain per step = 16 h-MFMAs + nonlinearity only. Triple-buffered x.
__global__ __launch_bounds__(512, 2)
void layer4_k(ConvArgs3 targ, ConvArgs3 iarg) {
  const bool is_tag = ((int)blockIdx.x < targ.nblk);
  const ConvArgs3& a = is_tag ? targ : iarg;
  const int blk  = is_tag ? (int)blockIdx.x : ((int)blockIdx.x - targ.nblk);
  const int tid  = threadIdx.x;
  const int wv   = tid >> 6;
  const int lane = tid & 63;
  const int n0   = blk * 16;
  const int K    = a.K;

  __shared__ __align__(16) uint16_t xs[3][2048];
  __shared__ __align__(16) uint16_t hs[2][2048];
  __shared__ float2 red[8][16];
  __shared__ int ids_s[16], lens_s[16];

  if (tid < 16) {
    int id = a.ord[n0 + tid];
    ids_s[tid]  = id;
    lens_s[tid] = a.len[id];
  }
  *reinterpret_cast<ushort4*>(&hs[0][tid * 4]) = make_ushort4(0, 0, 0, 0);
  __syncthreads();

  const int n  = lane & 15;
  const int dq = lane >> 4;
  const int d0 = wv * 16 + dq * 4;
  const int lenN = lens_s[n];
  const int pnode = tid >> 5, pq = tid & 31;
  const int pid  = ids_s[pnode];
  const int plen = lens_s[pnode];
  const int pidx = (pnode * 128 + pq * 4) ^ ((pnode & 7) << 3);

  int tmax = 1;
  #pragma unroll
  for (int b = 0; b < 16; b++) tmax = max(tmax, lens_s[b]);

  int offs[4];
  #pragma unroll
  for (int s = 0; s < 4; s++)
    offs[s] = (n * 128 + s * 32 + dq * 8) ^ ((n & 7) << 3);
  const int hwo = (n * 128 + d0) ^ ((n & 7) << 3);

  bfrag Ag[4][8];
  #pragma unroll
  for (int g = 0; g < 4; g++) {
    #pragma unroll
    for (int s = 0; s < 8; s++)
      Ag[g][s] = *reinterpret_cast<const bfrag*>(
          a.Wg + (size_t)((((wv * 4 + g) * 8 + s) * 64 + lane) * 8));
  }

  f32x4 bias4[4];
  #pragma unroll
  for (int g = 0; g < 4; g++) {
    f32x4 bi = *reinterpret_cast<const f32x4*>(a.bih + g * 128 + d0);
    f32x4 bh = *reinterpret_cast<const f32x4*>(a.bhh + g * 128 + d0);
    const float sc = (g == 2) ? TL2E : -L2E;
    bias4[g] = (bi + bh) * sc;
  }

  const int* nbrp = a.nbr + (size_t)pid * K;
  { // stage x_0, x_1
    *reinterpret_cast<ushort4*>(&xs[0][pidx]) =
        *reinterpret_cast<const ushort4*>(a.hsrc + (size_t)nbrp[0] * HD + pq * 4);
    if (plen > 1)
      *reinterpret_cast<ushort4*>(&xs[1][pidx]) =
          *reinterpret_cast<const ushort4*>(a.hsrc + (size_t)nbrp[1] * HD + pq * 4);
  }
  ushort4 xq = make_ushort4(0, 0, 0, 0);
  if (plen > 2)
    xq = *reinterpret_cast<const ushort4*>(a.hsrc + (size_t)nbrp[2] * HD + pq * 4);
  int idxn = (plen > 3) ? nbrp[3] : 0;
  __syncthreads();

  // Cx for t=0
  f32x4 Cx[4];
  #pragma unroll
  for (int g = 0; g < 4; g++) Cx[g] = bias4[g];
  #pragma unroll
  for (int s = 0; s < 4; s++) {
    bfrag bx = *reinterpret_cast<const bfrag*>(&xs[0][offs[s]]);
    #pragma unroll
    for (int g = 0; g < 4; g++)
      Cx[g] = __builtin_amdgcn_mfma_f32_16x16x32_bf16(Ag[g][s], bx, Cx[g], 0, 0, 0);
  }

  float cst[4] = {0.f, 0.f, 0.f, 0.f};
  uint2 hpk = {0u, 0u};

  for (int t = 0; t < tmax; ++t) {
    const int cur = t & 1, nxt = cur ^ 1;

    // dependent path: C = Cx_cur + Whh*h_t
    f32x4 C[4];
    #pragma unroll
    for (int g = 0; g < 4; g++) C[g] = Cx[g];
    #pragma unroll
    for (int s = 0; s < 4; s++) {
      bfrag bh = *reinterpret_cast<const bfrag*>(&hs[cur][offs[s]]);
      #pragma unroll
      for (int g = 0; g < 4; g++)
        C[g] = __builtin_amdgcn_mfma_f32_16x16x32_bf16(Ag[g][s + 4], bh, C[g], 0, 0, 0);
    }

    // independent path: Cx for t+1 (fills MFMA pipe during h-chain latency)
    if (t + 1 < tmax) {
      const uint16_t* xb = &xs[(t + 1) % 3][0];
      #pragma unroll
      for (int g = 0; g < 4; g++) Cx[g] = bias4[g];
      #pragma unroll
      for (int s = 0; s < 4; s++) {
        bfrag bx = *reinterpret_cast<const bfrag*>(&xb[offs[s]]);
        #pragma unroll
        for (int g = 0; g < 4; g++)
          Cx[g] = __builtin_amdgcn_mfma_f32_16x16x32_bf16(Ag[g][s], bx, Cx[g], 0, 0, 0);
      }
    }

    if (t < lenN) {
      float hv[4];
      #pragma unroll
      for (int r = 0; r < 4; r++) {
        const float iv = __builtin_amdgcn_rcpf(1.0f + exp2ft(C[0][r]));
        const float fv = __builtin_amdgcn_rcpf(1.0f + exp2ft(C[1][r]));
        const float gv = 1.0f - 2.0f * __builtin_amdgcn_rcpf(1.0f + exp2ft(C[2][r]));
        const float ov = __builtin_amdgcn_rcpf(1.0f + exp2ft(C[3][r]));
        const float cn = fmaf(fv, cst[r], iv * gv);
        cst[r] = cn;
        const float th = 1.0f - 2.0f * __builtin_amdgcn_rcpf(1.0f + exp2ft(cn * TL2E));
        hv[r] = ov * th;
      }
      hpk.x = cvt_pk_bf16(hv[0], hv[1]);
      hpk.y = cvt_pk_bf16(hv[2], hv[3]);
    }

    // stage x_{t+2} into slot (t+2)%3 (needed at step t+1 for Cx_{t+2})
    if (t + 2 < tmax) {
      if (t + 2 < plen)
        *reinterpret_cast<ushort4*>(&xs[(t + 2) % 3][pidx]) = xq;
      if (t + 3 < plen)
        xq = *reinterpret_cast<const ushort4*>(a.hsrc + (size_t)idxn * HD + pq * 4);
      idxn = (t + 4 < plen) ? nbrp[t + 4] : 0;
    }
    *reinterpret_cast<uint2*>(&hs[nxt][hwo]) = hpk;
    __syncthreads();
  }

  const int fin = tmax & 1;

  // ---- epilogue: out = hdst@Wself^T + hn@Wneigh^T + b (+LN for items) ----
  bfrag Ae[8];
  #pragma unroll
  for (int s = 0; s < 8; s++)
    Ae[s] = *reinterpret_cast<const bfrag*>(
        a.We + (size_t)(((wv * 8 + s) * 64 + lane) * 8));

  *reinterpret_cast<ushort4*>(&xs[0][pidx]) =
      *reinterpret_cast<const ushort4*>(a.hdst + (size_t)pid * HD + pq * 4);
  __syncthreads();

  f32x4 O = *reinterpret_cast<const f32x4*>(a.bvec + d0);
  #pragma unroll
  for (int s = 0; s < 4; s++) {
    bfrag bx = *reinterpret_cast<const bfrag*>(&xs[0][offs[s]]);
    O = __builtin_amdgcn_mfma_f32_16x16x32_bf16(Ae[s], bx, O, 0, 0, 0);
  }
  #pragma unroll
  for (int s = 0; s < 4; s++) {
    bfrag bh = *reinterpret_cast<const bfrag*>(&hs[fin][offs[s]]);
    O = __builtin_amdgcn_mfma_f32_16x16x32_bf16(Ae[s + 4], bh, O, 0, 0, 0);
  }

  const int oid = ids_s[n];
  if (!a.ln) {
    uint2 pk;
    pk.x = cvt_pk_bf16(O[0], O[1]);
    pk.y = cvt_pk_bf16(O[2], O[3]);
    *reinterpret_cast<uint2*>(a.outbf + (size_t)oid * HD + d0) = pk;
  } else {
    float s1 = O[0] + O[1] + O[2] + O[3];
    float s2 = O[0] * O[0] + O[1] * O[1] + O[2] * O[2] + O[3] * O[3];
    s1 += __shfl_xor(s1, 16); s2 += __shfl_xor(s2, 16);
    s1 += __shfl_xor(s1, 32); s2 += __shfl_xor(s2, 32);
    if (dq == 0) red[wv][n] = make_float2(s1, s2);
    __syncthreads();
    float m1 = 0.f, m2 = 0.f;
    #pragma unroll
    for (int w = 0; w < 8; w++) {
      float2 v = red[w][n];
      m1 += v.x; m2 += v.y;
    }
    const float mu   = m1 * (1.f / 128.f);
    const float var  = m2 * (1.f / 128.f) - mu * mu;
    const float istd = rsqrtf(var + 1e-5f);
    f32x4 gm = *reinterpret_cast<const f32x4*>(a.gamma + d0);
    f32x4 bt = *reinterpret_cast<const f32x4*>(a.beta + d0);
    float v[4];
    #pragma unroll
    for (int r = 0; r < 4; r++)
      v[r] = (O[r] - mu) * istd * gm[r] + bt[r];
    uint2 pk;
    pk.x = cvt_pk_bf16(v[0], v[1]);
    pk.y = cvt_pk_bf16(v[2], v[3]);
    *reinterpret_cast<uint2*>(a.outbf + (size_t)oid * HD + d0) = pk;
  }
}

// final Linear (no bias) + LeakyReLU, gathered by inv. Block = 16 outputs.
__global__ __launch_bounds__(512)
void final2_k(const uint16_t* __restrict__ hib, const int* __restrict__ inv,
              const uint16_t* __restrict__ fWf, float* __restrict__ out) {
  __shared__ __align__(16) uint16_t rs[2048];
  __shared__ int rid[16];
  const int tid = threadIdx.x, wv = tid >> 6, lane = tid & 63;
  const int i0 = blockIdx.x * 16;
  if (tid < 16) rid[tid] = inv[i0 + tid];
  __syncthreads();
  const int pnode = tid >> 5, pq = tid & 31;
  const int pidx = (pnode * 128 + pq * 4) ^ ((pnode & 7) << 3);
  *reinterpret_cast<ushort4*>(&rs[pidx]) =
      *reinterpret_cast<const ushort4*>(hib + (size_t)rid[pnode] * HD + pq * 4);
  __syncthreads();

  const int n = lane & 15, dq = lane >> 4;
  const int d0 = wv * 16 + dq * 4;
  bfrag Af[4];
  #pragma unroll
  for (int s = 0; s < 4; s++)
    Af[s] = *reinterpret_cast<const bfrag*>(fWf + (size_t)(((wv * 4 + s) * 64 + lane) * 8));

  f32x4 O = {0.f, 0.f, 0.f, 0.f};
  #pragma unroll
  for (int s = 0; s < 4; s++) {
    const int off = (n * 128 + s * 32 + dq * 8) ^ ((n & 7) << 3);
    bfrag b = *reinterpret_cast<const bfrag*>(&rs[off]);
    O = __builtin_amdgcn_mfma_f32_16x16x32_bf16(Af[s], b, O, 0, 0, 0);
  }
  float4 res;
  res.x = (O[0] > 0.f) ? O[0] : 0.01f * O[0];
  res.y = (O[1] > 0.f) ? O[1] : 0.01f * O[1];
  res.z = (O[2] > 0.f) ? O[2] : 0.01f * O[2];
  res.w = (O[3] > 0.f) ? O[3] : 0.01f * O[3];
  *reinterpret_cast<float4*>(out + (size_t)(i0 + n) * HD + d0) = res;
}

} // namespace

extern "C" void kernel_launch(void* const* d_in, const int* in_sizes, int n_in,
                              void* d_out, int out_size, void* d_ws, size_t ws_size,
                              hipStream_t stream) {
  (void)in_sizes; (void)n_in; (void)out_size; (void)ws_size;

  const int*   items      = (const int*)d_in[0];
  const int*   nbr_item   = (const int*)d_in[1];
  const int*   len_tag    = (const int*)d_in[2];
  const int*   nbr_tag    = (const int*)d_in[3];
  const int*   len_item   = (const int*)d_in[4];
  const float* item_table = (const float*)d_in[5];
  const float* tag_table  = (const float*)d_in[6];
  const float* Wih_as   = (const float*)d_in[7];
  const float* Whh_as   = (const float*)d_in[8];
  const float* bih_as   = (const float*)d_in[9];
  const float* bhh_as   = (const float*)d_in[10];
  const float* Wself_as  = (const float*)d_in[11];
  const float* Wneigh_as = (const float*)d_in[12];
  const float* b_as      = (const float*)d_in[13];
  const float* Wih_ras   = (const float*)d_in[14];
  const float* Whh_ras   = (const float*)d_in[15];
  const float* bih_ras   = (const float*)d_in[16];
  const float* bhh_ras   = (const float*)d_in[17];
  const float* Wself_ras  = (const float*)d_in[18];
  const float* Wneigh_ras = (const float*)d_in[19];
  const float* b_ras      = (const float*)d_in[20];
  const float* ln_gamma = (const float*)d_in[21];
  const float* ln_beta  = (const float*)d_in[22];
  const float* W_final  = (const float*)d_in[23];
  float* out = (float*)d_out;

  char* p = (char*)d_ws;
  auto take = [&](size_t bytes) -> char* {
    char* r = p;
    p += (bytes + 255) & ~(size_t)255;
    return r;
  };
  int* present = (int*)take((size_t)VOCAB * sizeof(int));
  int* rank    = (int*)take((size_t)(VOCAB + 1) * sizeof(int));
  int* invp    = (int*)take((size_t)N_ITEMS * sizeof(int));
  int* partial = (int*)take(64 * sizeof(int));
  uint16_t* hti0 = (uint16_t*)take((size_t)N_ITEMS * HD * 2);
  uint16_t* htiA = (uint16_t*)take((size_t)N_ITEMS * HD * 2);
  uint16_t* htiB = (uint16_t*)take((size_t)N_ITEMS * HD * 2);
  uint16_t* htt0 = (uint16_t*)take((size_t)N_TAGS * HD * 2);
  uint16_t* httA = (uint16_t*)take((size_t)N_TAGS * HD * 2);
  uint16_t* httB = (uint16_t*)take((size_t)N_TAGS * HD * 2);
  uint16_t* WgA = (uint16_t*)take((size_t)GWSZ * 2);
  uint16_t* WgR = (uint16_t*)take((size_t)GWSZ * 2);
  uint16_t* WeA = (uint16_t*)take((size_t)EWSZ * 2);
  uint16_t* WeR = (uint16_t*)take((size_t)EWSZ * 2);
  uint16_t* fWf = (uint16_t*)take((size_t)FWSZ * 2);
  int* hists = (int*)take((size_t)(KTAG + 1 + KITEM + 1) * sizeof(int));
  int* hist_tag  = hists;
  int* hist_item = hists + KTAG + 1;
  int* base_tag  = (int*)take((size_t)(KTAG + 1) * sizeof(int));
  int* base_item = (int*)take((size_t)(KITEM + 1) * sizeof(int));
  int* ord_tag   = (int*)take((size_t)N_TAGS * sizeof(int));
  int* ord_item  = (int*)take((size_t)N_ITEMS * sizeof(int));

  const int NHIST = KTAG + 1 + KITEM + 1;
  const int NPREP = NBPI + NCONV + N_TAGS + N_ITEMS;

  zero_k<<<(VOCAB + NHIST + 255) / 256, 256, 0, stream>>>(present, hists, NHIST);
  markhist_k<<<(N_TAGS + N_ITEMS + 255) / 256, 256, 0, stream>>>(
      items, present, len_tag, len_item, hist_tag, hist_item);
  scanA_k<<<NSCAN, 256, 0, stream>>>(present, partial, hist_tag, base_tag,
                                     hist_item, base_item);
  scanC_k<<<NSCAN, 256, 0, stream>>>(present, partial, rank);
  prep_k<<<(NPREP + 255) / 256, 256, 0, stream>>>(
      present, rank, items, item_table, tag_table, hti0, htt0, invp,
      Wih_as, Whh_as, Wih_ras, Whh_ras, Wself_as, Wneigh_as, Wself_ras, Wneigh_ras,
      W_final, WgA, WgR, WeA, WeR, fWf,
      len_tag, len_item, base_tag, base_item, ord_tag, ord_item);

  const uint16_t* hi_cur = hti0; uint16_t* hi_nxt = htiA;
  const uint16_t* ht_cur = htt0; uint16_t* ht_nxt = httA;

  for (int l = 0; l < NLAYER; ++l) {
    ConvArgs3 ta, ia;
    ta.hsrc = hi_cur; ta.hdst = ht_cur;
    ta.nbr = nbr_item; ta.len = len_tag; ta.ord = ord_tag;
    ta.Wg = WgA + (size_t)l * 131072; ta.We = WeA + (size_t)l * 32768;
    ta.bih = bih_as + (size_t)l * 512; ta.bhh = bhh_as + (size_t)l * 512;
    ta.bvec = b_as + (size_t)l * HD;
    ta.gamma = nullptr; ta.beta = nullptr;
    ta.outbf = ht_nxt; ta.K = KTAG; ta.ln = 0; ta.nblk = N_TAGS / 16;

    ia.hsrc = ht_cur; ia.hdst = hi_cur;
    ia.nbr = nbr_tag; ia.len = len_item; ia.ord = ord_item;
    ia.Wg = WgR + (size_t)l * 131072; ia.We = WeR + (size_t)l * 32768;
    ia.bih = bih_ras + (size_t)l * 512; ia.bhh = bhh_ras + (size_t)l * 512;
    ia.bvec = b_ras + (size_t)l * HD;
    ia.gamma = ln_gamma + (size_t)l * HD; ia.beta = ln_beta + (size_t)l * HD;
    ia.outbf = hi_nxt; ia.K = KITEM; ia.ln = 1; ia.nblk = N_ITEMS / 16;

    layer4_k<<<ta.nblk + ia.nblk, 512, 0, stream>>>(ta, ia);

    hi_cur = hi_nxt; hi_nxt = (hi_cur == htiA) ? htiB : htiA;
    ht_cur = ht_nxt; ht_nxt = (ht_cur == httA) ? httB : httA;
  }

  final2_k<<<N_ITEMS / 16, 512, 0, stream>>>(hi_cur, invp, fWf, out);
}